// Round 1
// baseline (7450.235 us; speedup 1.0000x reference)
//
#include <hip/hip_runtime.h>
#include <math.h>

#define HW 16384   // 128*128

__device__ __forceinline__ float gelu_exact(float x) {
    return 0.5f * x * (1.0f + erff(x * 0.70710678118654752f));
}

// ---------------- DWT: R [4,64,256,256] -> 4 subbands written as comb slices ----------------
__global__ __launch_bounds__(256) void dwt_kernel(const float* __restrict__ R,
                                                  float* __restrict__ comb) {
    int gid = blockIdx.x * 256 + threadIdx.x;          // over 4*64*128*128
    int j = gid & 127;
    int i = (gid >> 7) & 127;
    int c = (gid >> 14) & 63;
    int b = gid >> 20;
    const float* base = R + ((b * 64 + c) * 256 + 2 * i) * 256 + 2 * j;
    float a = base[0], bb = base[1];
    float cc = base[256], dd = base[257];
    float ll = (a + bb + cc + dd) * 0.5f;
    float lh = (cc + dd - a - bb) * 0.5f;
    float hl = (bb - a + dd - cc) * 0.5f;
    float hh = (a - bb - cc + dd) * 0.5f;
    float* o = comb + b * (256 * HW) + c * HW + i * 128 + j;
    o[0]        = ll;
    o[64 * HW]  = lh;
    o[128 * HW] = hl;
    o[192 * HW] = hh;
}

// ---------------- generic direct conv3x3, pad=1, optional exact GELU ----------------
template<int CIN, int COUT, int H, int W, bool GELU>
__global__ __launch_bounds__(256) void conv3x3_kernel(const float* __restrict__ in,
                                                      const float* __restrict__ wgt,
                                                      const float* __restrict__ bias,
                                                      float* __restrict__ out,
                                                      int in_bstride, int out_bstride) {
    constexpr int PLANE = H * W;
    constexpr int BPP = PLANE / 256;
    int uid = blockIdx.x;
    int xyb = (uid % BPP) * 256;                   // block-uniform
    int co  = (uid / BPP) % COUT;                  // block-uniform -> scalar weight loads
    int b   = uid / (BPP * COUT);
    int pos = xyb + (int)threadIdx.x;
    int y = pos / W;
    int x = pos % W;
    const float* ip = in + b * in_bstride;
    const float* wp = wgt + co * (CIN * 9);
    float acc = bias[co];
    for (int ci = 0; ci < CIN; ++ci) {
        const float* plane = ip + ci * PLANE;
        const float* wc = wp + ci * 9;
        #pragma unroll
        for (int dy = -1; dy <= 1; ++dy) {
            int yy = y + dy;
            if ((unsigned)yy < (unsigned)H) {
                const float* row = plane + yy * W;
                #pragma unroll
                for (int dx = -1; dx <= 1; ++dx) {
                    int xx = x + dx;
                    if ((unsigned)xx < (unsigned)W)
                        acc = fmaf(row[xx], wc[(dy + 1) * 3 + (dx + 1)], acc);
                }
            }
        }
    }
    if (GELU) acc = gelu_exact(acc);
    out[b * out_bstride + co * PLANE + pos] = acc;
}

// ---------------- conv2 (32->6) fused with 2x2 avg-pool and tanh*0.25 ----------------
__global__ __launch_bounds__(256) void conv2_pool_kernel(const float* __restrict__ o1,
                                                         const float* __restrict__ wgt,
                                                         const float* __restrict__ bias,
                                                         float* __restrict__ disp) {
    int gid = blockIdx.x * 256 + threadIdx.x;      // over 4*6*128*128
    int j = gid & 127;
    int i = (gid >> 7) & 127;
    int ch = (gid >> 14) % 6;                      // block-uniform
    int b  = gid / (6 * HW);
    const float* ip = o1 + b * (32 * 65536);
    const float* wp = wgt + ch * (32 * 9);
    float s4 = 0.0f;
    for (int ci = 0; ci < 32; ++ci) {
        const float* plane = ip + ci * 65536;
        const float* wc = wp + ci * 9;
        #pragma unroll
        for (int r = 0; r < 2; ++r) {
            #pragma unroll
            for (int s = 0; s < 2; ++s) {
                int y = 2 * i + r, x = 2 * j + s;
                #pragma unroll
                for (int dy = -1; dy <= 1; ++dy) {
                    int yy = y + dy;
                    if ((unsigned)yy < 256u) {
                        const float* row = plane + yy * 256;
                        #pragma unroll
                        for (int dx = -1; dx <= 1; ++dx) {
                            int xx = x + dx;
                            if ((unsigned)xx < 256u)
                                s4 = fmaf(row[xx], wc[(dy + 1) * 3 + (dx + 1)], s4);
                        }
                    }
                }
            }
        }
    }
    float pooled = 0.25f * s4 + bias[ch];
    disp[gid] = tanhf(pooled) * 0.25f;             // displacement, MAX_DISP folded in
}

// ---------------- deform: bilinear grid_sample, reflection, align_corners=True ----------------
__global__ __launch_bounds__(256) void deform_kernel(const float* __restrict__ sub, int sub_bstride,
                                                     const float* __restrict__ disp, int doff,
                                                     float* __restrict__ Z) {
    int gid = blockIdx.x * 256 + threadIdx.x;      // over 4*128*128
    int j = gid & 127;
    int i = (gid >> 7) & 127;
    int b = gid >> 14;
    const float* dp = disp + b * (6 * HW) + doff * HW + (i * 128 + j);
    float dx = dp[0];
    float dy = dp[HW];
    float gx = fmaf((float)j, 2.0f / 127.0f, -1.0f) + dx;
    float gy = fmaf((float)i, 2.0f / 127.0f, -1.0f) + dy;
    float ix = (gx + 1.0f) * 0.5f * 127.0f;
    float iy = (gy + 1.0f) * 0.5f * 127.0f;
    ix = fabsf(ix); ix = fmodf(ix, 254.0f); if (ix > 127.0f) ix = 254.0f - ix;
    iy = fabsf(iy); iy = fmodf(iy, 254.0f); if (iy > 127.0f) iy = 254.0f - iy;
    float x0f = floorf(ix), y0f = floorf(iy);
    float wx = ix - x0f, wy = iy - y0f;
    int x0 = min(max((int)x0f, 0), 127);
    int x1 = min(x0 + 1, 127);
    int y0 = min(max((int)y0f, 0), 127);
    int y1 = min(y0 + 1, 127);
    float w00 = (1.0f - wx) * (1.0f - wy), w01 = wx * (1.0f - wy);
    float w10 = (1.0f - wx) * wy,          w11 = wx * wy;
    int o00 = y0 * 128 + x0, o01 = y0 * 128 + x1;
    int o10 = y1 * 128 + x0, o11 = y1 * 128 + x1;
    const float* sp = sub + b * sub_bstride;
    float* zp = Z + b * (64 * HW) + i * 128 + j;
    for (int c = 0; c < 64; ++c) {
        const float* pl = sp + c * HW;
        zp[c * HW] = w00 * pl[o00] + w01 * pl[o01] + w10 * pl[o10] + w11 * pl[o11];
    }
}

// ---------------- LN + FFN + residual; lane = pixel, channels in registers ----------------
__global__ __launch_bounds__(256) void ln_ffn_kernel(const float* __restrict__ zin, int in_bstride,
                                                     float* __restrict__ out, int out_bstride,
                                                     const float* __restrict__ lnw,
                                                     const float* __restrict__ lnb,
                                                     const float* __restrict__ w1t,   // [256][64]
                                                     const float* __restrict__ b1,
                                                     const float* __restrict__ w2,    // [256][64]
                                                     const float* __restrict__ b2) {
    int gid = blockIdx.x * 256 + threadIdx.x;
    int lane = gid & 63;
    int wid = gid >> 6;
    int p0 = wid * 64;                             // pixel base, over 4*16384
    int b = p0 >> 14;
    int pp = (p0 & (HW - 1)) + lane;
    const float* zp = zin + b * in_bstride + pp;
    float z[64], zn[64], acc[64];
    #pragma unroll
    for (int c = 0; c < 64; ++c) z[c] = zp[c * HW];
    float mu = 0.0f;
    #pragma unroll
    for (int c = 0; c < 64; ++c) mu += z[c];
    mu *= (1.0f / 64.0f);
    float var = 0.0f;
    #pragma unroll
    for (int c = 0; c < 64; ++c) { float d = z[c] - mu; var = fmaf(d, d, var); }
    var *= (1.0f / 64.0f);
    float rstd = rsqrtf(var + 1e-5f);
    #pragma unroll
    for (int c = 0; c < 64; ++c) zn[c] = (z[c] - mu) * rstd * lnw[c] + lnb[c];
    #pragma unroll
    for (int c = 0; c < 64; ++c) acc[c] = 0.0f;
    #pragma unroll 4
    for (int jj = 0; jj < 256; ++jj) {
        const float* w1r = w1t + jj * 64;          // uniform -> s_load
        float h0 = 0.0f, h1 = 0.0f, h2 = 0.0f, h3 = 0.0f;
        #pragma unroll
        for (int c = 0; c < 64; c += 4) {
            h0 = fmaf(zn[c],     w1r[c],     h0);
            h1 = fmaf(zn[c + 1], w1r[c + 1], h1);
            h2 = fmaf(zn[c + 2], w1r[c + 2], h2);
            h3 = fmaf(zn[c + 3], w1r[c + 3], h3);
        }
        float h = gelu_exact(((h0 + h1) + (h2 + h3)) + b1[jj]);
        const float* w2r = w2 + jj * 64;           // uniform -> s_load
        #pragma unroll
        for (int c = 0; c < 64; ++c) acc[c] = fmaf(h, w2r[c], acc[c]);
    }
    float* op = out + b * out_bstride + pp;
    #pragma unroll
    for (int c = 0; c < 64; ++c) op[c * HW] = z[c] + acc[c] + b2[c];
}

// ---------------- fusion 1x1 conv 256->64 ----------------
__global__ __launch_bounds__(256) void conv1x1_kernel(const float* __restrict__ comb,
                                                      const float* __restrict__ wgt,
                                                      const float* __restrict__ bias,
                                                      float* __restrict__ out) {
    int gid = blockIdx.x * 256 + threadIdx.x;      // over 4*64*16384
    int pos = gid & (HW - 1);
    int co = (gid >> 14) & 63;                     // block-uniform
    int b = gid >> 20;
    const float* ip = comb + b * (256 * HW) + pos;
    const float* wp = wgt + co * 256;
    float a0 = 0.0f, a1 = 0.0f, a2 = 0.0f, a3 = 0.0f;
    #pragma unroll 4
    for (int ci = 0; ci < 256; ci += 4) {
        a0 = fmaf(ip[ci * HW],       wp[ci],     a0);
        a1 = fmaf(ip[(ci + 1) * HW], wp[ci + 1], a1);
        a2 = fmaf(ip[(ci + 2) * HW], wp[ci + 2], a2);
        a3 = fmaf(ip[(ci + 3) * HW], wp[ci + 3], a3);
    }
    out[gid] = ((a0 + a1) + (a2 + a3)) + bias[co];
}

// ---------------- w1 [64,256] -> w1t [256,64] ----------------
__global__ __launch_bounds__(256) void transpose_w1_kernel(const float* __restrict__ w1,
                                                           float* __restrict__ w1t) {
    int gid = blockIdx.x * 256 + threadIdx.x;      // 16384
    int jj = gid & 255;
    int c = gid >> 8;
    w1t[jj * 64 + c] = w1[c * 256 + jj];
}

extern "C" void kernel_launch(void* const* d_in, const int* in_sizes, int n_in,
                              void* d_out, int out_size, void* d_ws, size_t ws_size,
                              hipStream_t stream) {
    const float* R      = (const float*)d_in[0];
    const float* off_w1 = (const float*)d_in[1];
    const float* off_b1 = (const float*)d_in[2];
    const float* off_w2 = (const float*)d_in[3];
    const float* off_b2 = (const float*)d_in[4];
    const float* w_sub[4] = {(const float*)d_in[5], (const float*)d_in[7],
                             (const float*)d_in[9], (const float*)d_in[11]};
    const float* b_sub[4] = {(const float*)d_in[6], (const float*)d_in[8],
                             (const float*)d_in[10], (const float*)d_in[12]};
    const float* ln_w   = (const float*)d_in[13];
    const float* ln_b   = (const float*)d_in[14];
    const float* ffn_w1 = (const float*)d_in[15];
    const float* ffn_b1 = (const float*)d_in[16];
    const float* ffn_w2 = (const float*)d_in[17];
    const float* ffn_b2 = (const float*)d_in[18];
    const float* fus_w  = (const float*)d_in[19];
    const float* fus_b  = (const float*)d_in[20];

    // ws layout (floats). Lifetimes arranged so subbands live inside comb slices;
    // o1 overlaps Z/zbuf; zf overlaps Z. Total ~102 MB.
    float* ws   = (float*)d_ws;
    float* comb = ws;                               // 16,777,216 [4,256,128,128]
    float* o1   = ws + 16777216;                    // 8,388,608 [4,32,256,256] (offset stage only)
    float* Zb   = ws + 16777216;                    // 4,194,304 (after o1 dead)
    float* zbuf = ws + 16777216 + 4194304;          // 4,194,304
    float* disp = ws + 16777216 + 8388608;          // 393,216 [4,6,128,128]
    float* w1t  = disp + 393216;                    // 16,384
    float* zf   = Zb;                               // fusion conv out (Z dead by then)

    dwt_kernel<<<16384, 256, 0, stream>>>(R, comb);
    transpose_w1_kernel<<<64, 256, 0, stream>>>(ffn_w1, w1t);
    conv3x3_kernel<64, 32, 256, 256, true><<<32768, 256, 0, stream>>>(
        R, off_w1, off_b1, o1, 64 * 65536, 32 * 65536);
    conv2_pool_kernel<<<1536, 256, 0, stream>>>(o1, off_w2, off_b2, disp);

    for (int s = 0; s < 4; ++s) {
        const float* convin;
        int in_bs;
        if (s == 0) { convin = comb; in_bs = 256 * HW; }
        else {
            deform_kernel<<<256, 256, 0, stream>>>(comb + s * 64 * HW, 256 * HW,
                                                   disp, 2 * (s - 1), Zb);
            convin = Zb; in_bs = 64 * HW;
        }
        conv3x3_kernel<64, 64, 128, 128, false><<<16384, 256, 0, stream>>>(
            convin, w_sub[s], b_sub[s], zbuf, in_bs, 64 * HW);
        ln_ffn_kernel<<<256, 256, 0, stream>>>(zbuf, 64 * HW, comb + s * 64 * HW, 256 * HW,
                                               ln_w, ln_b, w1t, ffn_b1, ffn_w2, ffn_b2);
    }

    conv1x1_kernel<<<16384, 256, 0, stream>>>(comb, fus_w, fus_b, zf);
    ln_ffn_kernel<<<256, 256, 0, stream>>>(zf, 64 * HW, (float*)d_out, 64 * HW,
                                           ln_w, ln_b, w1t, ffn_b1, ffn_w2, ffn_b2);
}

// Round 2
// 3948.283 us; speedup vs baseline: 1.8870x; 1.8870x over previous
//
#include <hip/hip_runtime.h>
#include <math.h>

#define HW 16384   // 128*128

__device__ __forceinline__ float gelu_exact(float x) {
    return 0.5f * x * (1.0f + erff(x * 0.70710678118654752f));
}

// ---------------- weight prep: transposes + pooled conv2 weights ----------------
// A: ffn_w1 [64][256] -> w1t [256][64]                (16384)
// B: fus_w  [64][256] -> fus_wt [256][64]             (16384)
// C: w_sub  4x [64][64*9] -> wt_sub 4x [64*9][64]     (147456)
// D: off_w1 [32][64*9] -> wt_off1 [64*9][32]          (18432)
// E: off_w2 [6][32][9] -> w4_off2 [32][16][6] pooled  (3072)
__global__ __launch_bounds__(256) void prep_weights(
        const float* __restrict__ ffn_w1, float* __restrict__ w1t,
        const float* __restrict__ fus_w,  float* __restrict__ fus_wt,
        const float* __restrict__ w_ll, const float* __restrict__ w_lh,
        const float* __restrict__ w_hl, const float* __restrict__ w_hh,
        float* __restrict__ wt_sub,
        const float* __restrict__ off_w1, float* __restrict__ wt_off1,
        const float* __restrict__ off_w2, float* __restrict__ w4_off2) {
    int gid = blockIdx.x * 256 + threadIdx.x;
    if (gid < 16384) {
        int c = gid >> 8, j = gid & 255;
        w1t[j * 64 + c] = ffn_w1[c * 256 + j];
    } else if (gid < 32768) {
        int t = gid - 16384;
        int co = t >> 8, ci = t & 255;
        fus_wt[ci * 64 + co] = fus_w[co * 256 + ci];
    } else if (gid < 180224) {
        int t = gid - 32768;
        int s = t / 36864, r = t % 36864;
        int co = r & 63, q = r >> 6;            // q = ci*9+tap in [0,576)
        const float* w = (s == 0) ? w_ll : (s == 1) ? w_lh : (s == 2) ? w_hl : w_hh;
        wt_sub[s * 36864 + q * 64 + co] = w[co * 576 + q];
    } else if (gid < 198656) {
        int t = gid - 180224;
        int co = t & 31, q = t >> 5;
        wt_off1[q * 32 + co] = off_w1[co * 576 + q];
    } else if (gid < 201728) {
        int t = gid - 198656;
        int co = t % 6, q = t / 6;
        int v = q & 3, u = (q >> 2) & 3, ci = q >> 4;
        float sum = 0.0f;
        #pragma unroll
        for (int r = 0; r < 2; ++r)
            #pragma unroll
            for (int s2 = 0; s2 < 2; ++s2) {
                int du = u - r, dv = v - s2;
                if (du >= 0 && du < 3 && dv >= 0 && dv < 3)
                    sum += off_w2[co * 288 + ci * 9 + du * 3 + dv];
            }
        w4_off2[ci * 96 + (u * 4 + v) * 6 + co] = 0.25f * sum;
    }
}

// ---------------- DWT: R [4,64,256,256] -> 4 subbands written as comb slices ----------------
__global__ __launch_bounds__(256) void dwt_kernel(const float* __restrict__ R,
                                                  float* __restrict__ comb) {
    int gid = blockIdx.x * 256 + threadIdx.x;
    int j = gid & 127;
    int i = (gid >> 7) & 127;
    int c = (gid >> 14) & 63;
    int b = gid >> 20;
    const float* base = R + ((b * 64 + c) * 256 + 2 * i) * 256 + 2 * j;
    float a = base[0], bb = base[1];
    float cc = base[256], dd = base[257];
    float* o = comb + b * (256 * HW) + c * HW + i * 128 + j;
    o[0]        = (a + bb + cc + dd) * 0.5f;
    o[64 * HW]  = (cc + dd - a - bb) * 0.5f;
    o[128 * HW] = (bb - a + dd - cc) * 0.5f;
    o[192 * HW] = (a - bb - cc + dd) * 0.5f;
}

// ---------------- tiled conv3x3: block = 16x16 spatial tile, ALL COUT channels ----------------
// weights pre-transposed: wt[(ci*9+tap)*COUT + co]
template<int CIN, int COUT, int H, int W, bool GELU>
__global__ __launch_bounds__(256) void conv3x3_tiled(const float* __restrict__ in,
                                                     const float* __restrict__ wt,
                                                     const float* __restrict__ bias,
                                                     float* __restrict__ out,
                                                     int in_bstride, int out_bstride) {
    constexpr int PLANE = H * W;
    constexpr int TX = W / 16, TY = H / 16;
    constexpr int CH = 4;                       // cin chunk per LDS stage
    __shared__ float tile[CH * 18 * 18];
    int tid = threadIdx.x;
    int bx = blockIdx.x % TX;
    int by = (blockIdx.x / TX) % TY;
    int b  = blockIdx.x / (TX * TY);
    int lx = tid & 15, ly = tid >> 4;
    int ox = bx * 16 + lx, oy = by * 16 + ly;
    int x0 = bx * 16 - 1, y0 = by * 16 - 1;     // halo origin
    float acc[COUT];
    #pragma unroll
    for (int co = 0; co < COUT; ++co) acc[co] = 0.0f;
    const float* ip = in + b * in_bstride;
    for (int ci0 = 0; ci0 < CIN; ci0 += CH) {
        for (int idx = tid; idx < CH * 324; idx += 256) {
            int p = idx / 324, r = idx % 324;
            int ty = r / 18, tx = r % 18;
            int gy = y0 + ty, gx = x0 + tx;
            float v = 0.0f;
            if ((unsigned)gy < (unsigned)H && (unsigned)gx < (unsigned)W)
                v = ip[(ci0 + p) * PLANE + gy * W + gx];
            tile[idx] = v;
        }
        __syncthreads();
        #pragma unroll
        for (int p = 0; p < CH; ++p) {
            const float* wrow = wt + (ci0 + p) * 9 * COUT;
            const float* tp = tile + p * 324;
            #pragma unroll
            for (int tap = 0; tap < 9; ++tap) {
                int dy = tap / 3, dx = tap % 3;
                float v = tp[(ly + dy) * 18 + (lx + dx)];
                const float* wr = wrow + tap * COUT;
                #pragma unroll
                for (int co = 0; co < COUT; ++co)
                    acc[co] = fmaf(v, wr[co], acc[co]);
            }
        }
        __syncthreads();
    }
    float* op = out + b * out_bstride + oy * W + ox;
    #pragma unroll
    for (int co = 0; co < COUT; ++co) {
        float r = acc[co] + bias[co];
        if (GELU) r = gelu_exact(r);
        op[co * PLANE] = r;
    }
}

// ---------------- conv2(32->6) + 2x2 avg-pool + tanh*0.25, collapsed to 4x4 corr ----------------
// w4[ci*96 + (u*4+v)*6 + co], u,v in [0,4)
__global__ __launch_bounds__(256) void conv2_pool_tiled(const float* __restrict__ o1,
                                                        const float* __restrict__ w4,
                                                        const float* __restrict__ bias,
                                                        float* __restrict__ disp) {
    constexpr int CH = 2;
    __shared__ float tile[CH * 1156];           // 34x34 per plane
    int tid = threadIdx.x;
    int bx = blockIdx.x & 7;
    int by = (blockIdx.x >> 3) & 7;
    int b  = blockIdx.x >> 6;
    int lx = tid & 15, ly = tid >> 4;
    int i = by * 16 + ly, j = bx * 16 + lx;     // half-res output coords
    int gy0 = by * 32 - 1, gx0 = bx * 32 - 1;
    float acc[6];
    #pragma unroll
    for (int co = 0; co < 6; ++co) acc[co] = 0.0f;
    const float* ip = o1 + b * (32 * 65536);
    for (int ci0 = 0; ci0 < 32; ci0 += CH) {
        for (int idx = tid; idx < CH * 1156; idx += 256) {
            int p = idx / 1156, r = idx % 1156;
            int ty = r / 34, tx = r % 34;
            int gy = gy0 + ty, gx = gx0 + tx;
            float v = 0.0f;
            if ((unsigned)gy < 256u && (unsigned)gx < 256u)
                v = ip[(ci0 + p) * 65536 + gy * 256 + gx];
            tile[idx] = v;
        }
        __syncthreads();
        #pragma unroll
        for (int p = 0; p < CH; ++p) {
            const float* wrow = w4 + (ci0 + p) * 96;
            const float* base = tile + p * 1156 + (2 * ly) * 34 + 2 * lx;
            #pragma unroll
            for (int u = 0; u < 4; ++u)
                #pragma unroll
                for (int v = 0; v < 4; ++v) {
                    float val = base[u * 34 + v];
                    const float* wr = wrow + (u * 4 + v) * 6;
                    #pragma unroll
                    for (int co = 0; co < 6; ++co)
                        acc[co] = fmaf(val, wr[co], acc[co]);
                }
        }
        __syncthreads();
    }
    #pragma unroll
    for (int co = 0; co < 6; ++co) {
        float pooled = acc[co] + bias[co];
        disp[b * (6 * HW) + co * HW + i * 128 + j] = tanhf(pooled) * 0.25f;
    }
}

// ---------------- deform: bilinear grid_sample, reflection, align_corners=True ----------------
__global__ __launch_bounds__(256) void deform_kernel(const float* __restrict__ sub, int sub_bstride,
                                                     const float* __restrict__ disp, int doff,
                                                     float* __restrict__ Z) {
    int gid = blockIdx.x * 256 + threadIdx.x;      // over 4*128*128
    int j = gid & 127;
    int i = (gid >> 7) & 127;
    int b = gid >> 14;
    const float* dp = disp + b * (6 * HW) + doff * HW + (i * 128 + j);
    float dx = dp[0];
    float dy = dp[HW];
    float gx = fmaf((float)j, 2.0f / 127.0f, -1.0f) + dx;
    float gy = fmaf((float)i, 2.0f / 127.0f, -1.0f) + dy;
    float ix = (gx + 1.0f) * 0.5f * 127.0f;
    float iy = (gy + 1.0f) * 0.5f * 127.0f;
    ix = fabsf(ix); ix = fmodf(ix, 254.0f); if (ix > 127.0f) ix = 254.0f - ix;
    iy = fabsf(iy); iy = fmodf(iy, 254.0f); if (iy > 127.0f) iy = 254.0f - iy;
    float x0f = floorf(ix), y0f = floorf(iy);
    float wx = ix - x0f, wy = iy - y0f;
    int x0 = min(max((int)x0f, 0), 127);
    int x1 = min(x0 + 1, 127);
    int y0 = min(max((int)y0f, 0), 127);
    int y1 = min(y0 + 1, 127);
    float w00 = (1.0f - wx) * (1.0f - wy), w01 = wx * (1.0f - wy);
    float w10 = (1.0f - wx) * wy,          w11 = wx * wy;
    int o00 = y0 * 128 + x0, o01 = y0 * 128 + x1;
    int o10 = y1 * 128 + x0, o11 = y1 * 128 + x1;
    const float* sp = sub + b * sub_bstride;
    float* zp = Z + b * (64 * HW) + i * 128 + j;
    for (int c = 0; c < 64; ++c) {
        const float* pl = sp + c * HW;
        zp[c * HW] = w00 * pl[o00] + w01 * pl[o01] + w10 * pl[o10] + w11 * pl[o11];
    }
}

// ---------------- LN + FFN + residual; lane = pixel, channels in registers ----------------
__global__ __launch_bounds__(256) void ln_ffn_kernel(const float* __restrict__ zin, int in_bstride,
                                                     float* __restrict__ out, int out_bstride,
                                                     const float* __restrict__ lnw,
                                                     const float* __restrict__ lnb,
                                                     const float* __restrict__ w1t,   // [256][64]
                                                     const float* __restrict__ b1,
                                                     const float* __restrict__ w2,    // [256][64]
                                                     const float* __restrict__ b2) {
    int gid = blockIdx.x * 256 + threadIdx.x;
    int lane = gid & 63;
    int wid = gid >> 6;
    int p0 = wid * 64;
    int b = p0 >> 14;
    int pp = (p0 & (HW - 1)) + lane;
    const float* zp = zin + b * in_bstride + pp;
    float z[64];
    #pragma unroll
    for (int c = 0; c < 64; ++c) z[c] = zp[c * HW];
    float mu = 0.0f;
    #pragma unroll
    for (int c = 0; c < 64; ++c) mu += z[c];
    mu *= (1.0f / 64.0f);
    float var = 0.0f;
    #pragma unroll
    for (int c = 0; c < 64; ++c) { float d = z[c] - mu; var = fmaf(d, d, var); }
    var *= (1.0f / 64.0f);
    float rstd = rsqrtf(var + 1e-5f);
    float zn[64], acc[64];
    #pragma unroll
    for (int c = 0; c < 64; ++c) zn[c] = (z[c] - mu) * rstd * lnw[c] + lnb[c];
    #pragma unroll
    for (int c = 0; c < 64; ++c) acc[c] = z[c] + b2[c];   // residual + out-bias; z dies here
    #pragma unroll 4
    for (int jj = 0; jj < 256; ++jj) {
        const float* w1r = w1t + jj * 64;          // uniform -> s_load
        float h0 = 0.0f, h1 = 0.0f, h2 = 0.0f, h3 = 0.0f;
        #pragma unroll
        for (int c = 0; c < 64; c += 4) {
            h0 = fmaf(zn[c],     w1r[c],     h0);
            h1 = fmaf(zn[c + 1], w1r[c + 1], h1);
            h2 = fmaf(zn[c + 2], w1r[c + 2], h2);
            h3 = fmaf(zn[c + 3], w1r[c + 3], h3);
        }
        float h = gelu_exact(((h0 + h1) + (h2 + h3)) + b1[jj]);
        const float* w2r = w2 + jj * 64;           // uniform -> s_load
        #pragma unroll
        for (int c = 0; c < 64; ++c) acc[c] = fmaf(h, w2r[c], acc[c]);
    }
    float* op = out + b * out_bstride + pp;
    #pragma unroll
    for (int c = 0; c < 64; ++c) op[c * HW] = acc[c];
}

// ---------------- fusion 1x1 conv 256->64: block = 256 px, all co, reads comb once ----------------
__global__ __launch_bounds__(256) void conv1x1_tiled(const float* __restrict__ comb,
                                                     const float* __restrict__ fus_wt, // [256][64]
                                                     const float* __restrict__ bias,
                                                     float* __restrict__ out) {
    int gid = blockIdx.x * 256 + threadIdx.x;      // over 4*16384 pixels
    int b = gid >> 14;
    int pp = gid & (HW - 1);
    const float* ip = comb + b * (256 * HW) + pp;
    float acc[64];
    #pragma unroll
    for (int co = 0; co < 64; ++co) acc[co] = bias[co];
    #pragma unroll 4
    for (int ci = 0; ci < 256; ++ci) {
        float v = ip[ci * HW];
        const float* wr = fus_wt + ci * 64;        // uniform -> s_load
        #pragma unroll
        for (int co = 0; co < 64; ++co) acc[co] = fmaf(v, wr[co], acc[co]);
    }
    float* op = out + b * (64 * HW) + pp;
    #pragma unroll
    for (int co = 0; co < 64; ++co) op[co * HW] = acc[co];
}

extern "C" void kernel_launch(void* const* d_in, const int* in_sizes, int n_in,
                              void* d_out, int out_size, void* d_ws, size_t ws_size,
                              hipStream_t stream) {
    const float* R      = (const float*)d_in[0];
    const float* off_w1 = (const float*)d_in[1];
    const float* off_b1 = (const float*)d_in[2];
    const float* off_w2 = (const float*)d_in[3];
    const float* off_b2 = (const float*)d_in[4];
    const float* w_sub[4] = {(const float*)d_in[5], (const float*)d_in[7],
                             (const float*)d_in[9], (const float*)d_in[11]};
    const float* b_sub[4] = {(const float*)d_in[6], (const float*)d_in[8],
                             (const float*)d_in[10], (const float*)d_in[12]};
    const float* ln_w   = (const float*)d_in[13];
    const float* ln_b   = (const float*)d_in[14];
    const float* ffn_w1 = (const float*)d_in[15];
    const float* ffn_b1 = (const float*)d_in[16];
    const float* ffn_w2 = (const float*)d_in[17];
    const float* ffn_b2 = (const float*)d_in[18];
    const float* fus_w  = (const float*)d_in[19];
    const float* fus_b  = (const float*)d_in[20];

    // ws layout (floats), ~98.3 MB total:
    float* ws      = (float*)d_ws;
    float* comb    = ws;                         // [4,256,128,128] = 16,777,216
    float* o1      = ws + 16777216;              // [4,32,256,256]  =  8,388,608 (offset stage)
    float* Zb      = ws + 16777216;              // [4,64,128,128]  =  4,194,304 (after o1 dead)
    float* zbuf    = ws + 16777216 + 4194304;    // [4,64,128,128]  =  4,194,304
    float* disp    = ws + 25165824;              // [4,6,128,128]   =    393,216
    float* w1t     = ws + 25559040;              // 16,384
    float* fus_wt  = ws + 25575424;              // 16,384
    float* wt_sub  = ws + 25591808;              // 147,456
    float* wt_off1 = ws + 25739264;              // 18,432
    float* w4_off2 = ws + 25757696;              // 3,072
    float* zf      = Zb;                         // fusion conv out (Z dead by then)

    prep_weights<<<789, 256, 0, stream>>>(ffn_w1, w1t, fus_w, fus_wt,
                                          w_sub[0], w_sub[1], w_sub[2], w_sub[3], wt_sub,
                                          off_w1, wt_off1, off_w2, w4_off2);
    dwt_kernel<<<16384, 256, 0, stream>>>(R, comb);
    conv3x3_tiled<64, 32, 256, 256, true><<<1024, 256, 0, stream>>>(
        R, wt_off1, off_b1, o1, 64 * 65536, 32 * 65536);
    conv2_pool_tiled<<<256, 256, 0, stream>>>(o1, w4_off2, off_b2, disp);

    for (int s = 0; s < 4; ++s) {
        const float* convin;
        int in_bs;
        if (s == 0) { convin = comb; in_bs = 256 * HW; }
        else {
            deform_kernel<<<256, 256, 0, stream>>>(comb + s * 64 * HW, 256 * HW,
                                                   disp, 2 * (s - 1), Zb);
            convin = Zb; in_bs = 64 * HW;
        }
        conv3x3_tiled<64, 64, 128, 128, false><<<256, 256, 0, stream>>>(
            convin, wt_sub + s * 36864, b_sub[s], zbuf, in_bs, 64 * HW);
        ln_ffn_kernel<<<256, 256, 0, stream>>>(zbuf, 64 * HW, comb + s * 64 * HW, 256 * HW,
                                               ln_w, ln_b, w1t, ffn_b1, ffn_w2, ffn_b2);
    }

    conv1x1_tiled<<<256, 256, 0, stream>>>(comb, fus_wt, fus_b, zf);
    ln_ffn_kernel<<<256, 256, 0, stream>>>(zf, 64 * HW, (float*)d_out, 64 * HW,
                                           ln_w, ln_b, w1t, ffn_b1, ffn_w2, ffn_b2);
}

// Round 3
// 2247.333 us; speedup vs baseline: 3.3151x; 1.7569x over previous
//
#include <hip/hip_runtime.h>
#include <math.h>

#define HW 16384   // 128*128

typedef __attribute__((ext_vector_type(8))) short short8;
typedef __attribute__((ext_vector_type(4))) float f32x4;
typedef __attribute__((ext_vector_type(4))) unsigned int u32x4;
typedef __attribute__((ext_vector_type(2))) unsigned int u32x2;

union V4S8 { u32x4 u; short8 s; };

__device__ __forceinline__ float gelu_exact(float x) {
    return 0.5f * x * (1.0f + erff(x * 0.70710678118654752f));
}

__device__ __forceinline__ unsigned short f2bf(float x) {
    unsigned int u = __float_as_uint(x);
    u = (u + 0x7FFFu + ((u >> 16) & 1u)) >> 16;
    return (unsigned short)u;
}
__device__ __forceinline__ unsigned int pack2bf(float lo, float hi) {
    return (unsigned int)f2bf(lo) | ((unsigned int)f2bf(hi) << 16);
}

// ---------------- weight prep ----------------
// [0,16384):        w1b  bf16 [256 h][64 c]   = ffn_w1^T
// [16384,32768):    w2tb bf16 [64 co][256 h]  = ffn_w2^T
// [32768,49152):    fus_wt fp32 [256 ci][64 co]
// [49152,196608):   wt_sub 4x [576 q][64 co]
// [196608,215040):  wt_off1 [576 q][32 co]
// [215040,218112):  w4_off2 [32 ci][16 uv][6 co] pooled
__global__ __launch_bounds__(256) void prep_weights(
        const float* __restrict__ ffn_w1, unsigned short* __restrict__ w1b,
        const float* __restrict__ ffn_w2, unsigned short* __restrict__ w2tb,
        const float* __restrict__ fus_w,  float* __restrict__ fus_wt,
        const float* __restrict__ w_ll, const float* __restrict__ w_lh,
        const float* __restrict__ w_hl, const float* __restrict__ w_hh,
        float* __restrict__ wt_sub,
        const float* __restrict__ off_w1, float* __restrict__ wt_off1,
        const float* __restrict__ off_w2, float* __restrict__ w4_off2) {
    int gid = blockIdx.x * 256 + threadIdx.x;
    if (gid < 16384) {
        int h = gid >> 6, c = gid & 63;
        w1b[gid] = f2bf(ffn_w1[c * 256 + h]);
    } else if (gid < 32768) {
        int t = gid - 16384;
        int co = t >> 8, h = t & 255;
        w2tb[t] = f2bf(ffn_w2[h * 64 + co]);
    } else if (gid < 49152) {
        int t = gid - 32768;
        int co = t >> 8, ci = t & 255;
        fus_wt[ci * 64 + co] = fus_w[co * 256 + ci];
    } else if (gid < 196608) {
        int t = gid - 49152;
        int s = t / 36864, r = t % 36864;
        int co = r & 63, q = r >> 6;
        const float* w = (s == 0) ? w_ll : (s == 1) ? w_lh : (s == 2) ? w_hl : w_hh;
        wt_sub[s * 36864 + q * 64 + co] = w[co * 576 + q];
    } else if (gid < 215040) {
        int t = gid - 196608;
        int co = t & 31, q = t >> 5;
        wt_off1[q * 32 + co] = off_w1[co * 576 + q];
    } else if (gid < 218112) {
        int t = gid - 215040;
        int co = t % 6, q = t / 6;
        int v = q & 3, u = (q >> 2) & 3, ci = q >> 4;
        float sum = 0.0f;
        #pragma unroll
        for (int r = 0; r < 2; ++r)
            #pragma unroll
            for (int s2 = 0; s2 < 2; ++s2) {
                int du = u - r, dv = v - s2;
                if (du >= 0 && du < 3 && dv >= 0 && dv < 3)
                    sum += off_w2[co * 288 + ci * 9 + du * 3 + dv];
            }
        w4_off2[ci * 96 + (u * 4 + v) * 6 + co] = 0.25f * sum;
    }
}

// ---------------- DWT ----------------
__global__ __launch_bounds__(256) void dwt_kernel(const float* __restrict__ R,
                                                  float* __restrict__ comb) {
    int gid = blockIdx.x * 256 + threadIdx.x;
    int j = gid & 127;
    int i = (gid >> 7) & 127;
    int c = (gid >> 14) & 63;
    int b = gid >> 20;
    const float* base = R + ((b * 64 + c) * 256 + 2 * i) * 256 + 2 * j;
    float a = base[0], bb = base[1];
    float cc = base[256], dd = base[257];
    float* o = comb + b * (256 * HW) + c * HW + i * 128 + j;
    o[0]        = (a + bb + cc + dd) * 0.5f;
    o[64 * HW]  = (cc + dd - a - bb) * 0.5f;
    o[128 * HW] = (bb - a + dd - cc) * 0.5f;
    o[192 * HW] = (a - bb - cc + dd) * 0.5f;
}

// ---------------- tiled conv3x3 (unchanged) ----------------
template<int CIN, int COUT, int H, int W, bool GELU>
__global__ __launch_bounds__(256) void conv3x3_tiled(const float* __restrict__ in,
                                                     const float* __restrict__ wt,
                                                     const float* __restrict__ bias,
                                                     float* __restrict__ out,
                                                     int in_bstride, int out_bstride) {
    constexpr int PLANE = H * W;
    constexpr int TX = W / 16, TY = H / 16;
    constexpr int CH = 4;
    __shared__ float tile[CH * 18 * 18];
    int tid = threadIdx.x;
    int bx = blockIdx.x % TX;
    int by = (blockIdx.x / TX) % TY;
    int b  = blockIdx.x / (TX * TY);
    int lx = tid & 15, ly = tid >> 4;
    int ox = bx * 16 + lx, oy = by * 16 + ly;
    int x0 = bx * 16 - 1, y0 = by * 16 - 1;
    float acc[COUT];
    #pragma unroll
    for (int co = 0; co < COUT; ++co) acc[co] = 0.0f;
    const float* ip = in + b * in_bstride;
    for (int ci0 = 0; ci0 < CIN; ci0 += CH) {
        for (int idx = tid; idx < CH * 324; idx += 256) {
            int p = idx / 324, r = idx % 324;
            int ty = r / 18, tx = r % 18;
            int gy = y0 + ty, gx = x0 + tx;
            float v = 0.0f;
            if ((unsigned)gy < (unsigned)H && (unsigned)gx < (unsigned)W)
                v = ip[(ci0 + p) * PLANE + gy * W + gx];
            tile[idx] = v;
        }
        __syncthreads();
        #pragma unroll
        for (int p = 0; p < CH; ++p) {
            const float* wrow = wt + (ci0 + p) * 9 * COUT;
            const float* tp = tile + p * 324;
            #pragma unroll
            for (int tap = 0; tap < 9; ++tap) {
                int dy = tap / 3, dx = tap % 3;
                float v = tp[(ly + dy) * 18 + (lx + dx)];
                const float* wr = wrow + tap * COUT;
                #pragma unroll
                for (int co = 0; co < COUT; ++co)
                    acc[co] = fmaf(v, wr[co], acc[co]);
            }
        }
        __syncthreads();
    }
    float* op = out + b * out_bstride + oy * W + ox;
    #pragma unroll
    for (int co = 0; co < COUT; ++co) {
        float r = acc[co] + bias[co];
        if (GELU) r = gelu_exact(r);
        op[co * PLANE] = r;
    }
}

// ---------------- conv2 + pool + tanh (unchanged) ----------------
__global__ __launch_bounds__(256) void conv2_pool_tiled(const float* __restrict__ o1,
                                                        const float* __restrict__ w4,
                                                        const float* __restrict__ bias,
                                                        float* __restrict__ disp) {
    constexpr int CH = 2;
    __shared__ float tile[CH * 1156];
    int tid = threadIdx.x;
    int bx = blockIdx.x & 7;
    int by = (blockIdx.x >> 3) & 7;
    int b  = blockIdx.x >> 6;
    int lx = tid & 15, ly = tid >> 4;
    int i = by * 16 + ly, j = bx * 16 + lx;
    int gy0 = by * 32 - 1, gx0 = bx * 32 - 1;
    float acc[6];
    #pragma unroll
    for (int co = 0; co < 6; ++co) acc[co] = 0.0f;
    const float* ip = o1 + b * (32 * 65536);
    for (int ci0 = 0; ci0 < 32; ci0 += CH) {
        for (int idx = tid; idx < CH * 1156; idx += 256) {
            int p = idx / 1156, r = idx % 1156;
            int ty = r / 34, tx = r % 34;
            int gy = gy0 + ty, gx = gx0 + tx;
            float v = 0.0f;
            if ((unsigned)gy < 256u && (unsigned)gx < 256u)
                v = ip[(ci0 + p) * 65536 + gy * 256 + gx];
            tile[idx] = v;
        }
        __syncthreads();
        #pragma unroll
        for (int p = 0; p < CH; ++p) {
            const float* wrow = w4 + (ci0 + p) * 96;
            const float* base = tile + p * 1156 + (2 * ly) * 34 + 2 * lx;
            #pragma unroll
            for (int u = 0; u < 4; ++u)
                #pragma unroll
                for (int v = 0; v < 4; ++v) {
                    float val = base[u * 34 + v];
                    const float* wr = wrow + (u * 4 + v) * 6;
                    #pragma unroll
                    for (int co = 0; co < 6; ++co)
                        acc[co] = fmaf(val, wr[co], acc[co]);
                }
        }
        __syncthreads();
    }
    #pragma unroll
    for (int co = 0; co < 6; ++co) {
        float pooled = acc[co] + bias[co];
        disp[b * (6 * HW) + co * HW + i * 128 + j] = tanhf(pooled) * 0.25f;
    }
}

// ---------------- deform (unchanged) ----------------
__global__ __launch_bounds__(256) void deform_kernel(const float* __restrict__ sub, int sub_bstride,
                                                     const float* __restrict__ disp, int doff,
                                                     float* __restrict__ Z) {
    int gid = blockIdx.x * 256 + threadIdx.x;
    int j = gid & 127;
    int i = (gid >> 7) & 127;
    int b = gid >> 14;
    const float* dp = disp + b * (6 * HW) + doff * HW + (i * 128 + j);
    float dx = dp[0];
    float dy = dp[HW];
    float gx = fmaf((float)j, 2.0f / 127.0f, -1.0f) + dx;
    float gy = fmaf((float)i, 2.0f / 127.0f, -1.0f) + dy;
    float ix = (gx + 1.0f) * 0.5f * 127.0f;
    float iy = (gy + 1.0f) * 0.5f * 127.0f;
    ix = fabsf(ix); ix = fmodf(ix, 254.0f); if (ix > 127.0f) ix = 254.0f - ix;
    iy = fabsf(iy); iy = fmodf(iy, 254.0f); if (iy > 127.0f) iy = 254.0f - iy;
    float x0f = floorf(ix), y0f = floorf(iy);
    float wx = ix - x0f, wy = iy - y0f;
    int x0 = min(max((int)x0f, 0), 127);
    int x1 = min(x0 + 1, 127);
    int y0 = min(max((int)y0f, 0), 127);
    int y1 = min(y0 + 1, 127);
    float w00 = (1.0f - wx) * (1.0f - wy), w01 = wx * (1.0f - wy);
    float w10 = (1.0f - wx) * wy,          w11 = wx * wy;
    int o00 = y0 * 128 + x0, o01 = y0 * 128 + x1;
    int o10 = y1 * 128 + x0, o11 = y1 * 128 + x1;
    const float* sp = sub + b * sub_bstride;
    float* zp = Z + b * (64 * HW) + i * 128 + j;
    for (int c = 0; c < 64; ++c) {
        const float* pl = sp + c * HW;
        zp[c * HW] = w00 * pl[o00] + w01 * pl[o01] + w10 * pl[o10] + w11 * pl[o11];
    }
}

// ---------------- LN + FFN via MFMA ----------------
// Wave = 16 pixels (m=lane&15), quad q = lane>>4.
// GEMM1 computes H^T = W1^T (A) x zn^T (B): C/D gives lane 4 CONSECUTIVE h per
// tile for pixel m -> vectorized ds_write_b64; GEMM2 A-frags are contiguous
// 16B ds_read_b128 from the same buffer. One barrier total.
__global__ __launch_bounds__(256) void ln_ffn_mfma(
        const float* __restrict__ zin, int in_bstride,
        float* __restrict__ out, int out_bstride,
        const float* __restrict__ lnw, const float* __restrict__ lnb,
        const unsigned short* __restrict__ w1b,   // [256 h][64 c] bf16
        const float* __restrict__ b1,
        const unsigned short* __restrict__ w2tb,  // [64 co][256 h] bf16
        const float* __restrict__ b2) {
    __shared__ __align__(16) unsigned short Hs[4][16 * 264];
    int tid = threadIdx.x;
    int w = tid >> 6, lane = tid & 63;
    int q = lane >> 4, m = lane & 15;
    int gidpx = blockIdx.x * 64 + w * 16;
    int b = gidpx >> 14;
    int pp0 = gidpx & (HW - 1);
    const float* zb = zin + (size_t)b * in_bstride;
    int p = pp0 + m;
    int clo = q * 8;

    // --- LayerNorm: lane holds 16 channels of pixel m ---
    float zv[16];
    #pragma unroll
    for (int i = 0; i < 8; ++i) zv[i] = zb[(clo + i) * HW + p];
    #pragma unroll
    for (int i = 0; i < 8; ++i) zv[8 + i] = zb[(32 + clo + i) * HW + p];
    float s = 0.0f, ss = 0.0f;
    #pragma unroll
    for (int i = 0; i < 16; ++i) { s += zv[i]; ss = fmaf(zv[i], zv[i], ss); }
    s  += __shfl_xor(s, 16);  s  += __shfl_xor(s, 32);
    ss += __shfl_xor(ss, 16); ss += __shfl_xor(ss, 32);
    float mu = s * (1.0f / 64.0f);
    float var = ss * (1.0f / 64.0f) - mu * mu;
    float rstd = rsqrtf(var + 1e-5f);
    short8 znf0, znf1;
    #pragma unroll
    for (int i = 0; i < 8; ++i) {
        float g = (zv[i] - mu) * rstd * lnw[clo + i] + lnb[clo + i];
        znf0[i] = (short)f2bf(g);
        float g2 = (zv[8 + i] - mu) * rstd * lnw[32 + clo + i] + lnb[32 + clo + i];
        znf1[i] = (short)f2bf(g2);
    }

    // --- GEMM1: H^T[256][16px], 16 ht tiles x K=64 ---
    f32x4 Ht[16];
    #pragma unroll
    for (int ht = 0; ht < 16; ++ht) {
        f32x4 d = {0.0f, 0.0f, 0.0f, 0.0f};
        V4S8 a0, a1;
        a0.u = *(const u32x4*)(w1b + (ht * 16 + m) * 64 + q * 8);
        a1.u = *(const u32x4*)(w1b + (ht * 16 + m) * 64 + 32 + q * 8);
        d = __builtin_amdgcn_mfma_f32_16x16x32_bf16(a0.s, znf0, d, 0, 0, 0);
        d = __builtin_amdgcn_mfma_f32_16x16x32_bf16(a1.s, znf1, d, 0, 0, 0);
        Ht[ht] = d;
    }

    // --- bias + gelu + stage H to LDS (row-major [px][h], pad 264) ---
    unsigned short* hp = &Hs[w][0];
    #pragma unroll
    for (int ht = 0; ht < 16; ++ht) {
        const f32x4 bv = *(const f32x4*)(b1 + ht * 16 + q * 4);
        float h0 = gelu_exact(Ht[ht][0] + bv[0]);
        float h1 = gelu_exact(Ht[ht][1] + bv[1]);
        float h2 = gelu_exact(Ht[ht][2] + bv[2]);
        float h3 = gelu_exact(Ht[ht][3] + bv[3]);
        u32x2 pk;
        pk[0] = pack2bf(h0, h1);
        pk[1] = pack2bf(h2, h3);
        *(u32x2*)(hp + m * 264 + ht * 16 + q * 4) = pk;
    }
    __syncthreads();

    // --- GEMM2: F[16px][64co] = H[16][256] x W2[256][64] ---
    f32x4 F[4];
    #pragma unroll
    for (int nt = 0; nt < 4; ++nt) F[nt] = (f32x4){0.0f, 0.0f, 0.0f, 0.0f};
    #pragma unroll
    for (int kt = 0; kt < 8; ++kt) {
        V4S8 af;
        af.u = *(const u32x4*)(hp + m * 264 + kt * 32 + q * 8);
        #pragma unroll
        for (int nt = 0; nt < 4; ++nt) {
            V4S8 bf_;
            bf_.u = *(const u32x4*)(w2tb + (nt * 16 + m) * 256 + kt * 32 + q * 8);
            F[nt] = __builtin_amdgcn_mfma_f32_16x16x32_bf16(af.s, bf_.s, F[nt], 0, 0, 0);
        }
    }

    // --- epilogue: out = z + F + b2 ---
    float* ob = out + (size_t)b * out_bstride;
    #pragma unroll
    for (int nt = 0; nt < 4; ++nt) {
        int co = nt * 16 + m;
        const f32x4 zr = *(const f32x4*)(zb + co * HW + pp0 + q * 4);
        float bias = b2[co];
        f32x4 r;
        #pragma unroll
        for (int k = 0; k < 4; ++k) r[k] = zr[k] + F[nt][k] + bias;
        *(f32x4*)(ob + co * HW + pp0 + q * 4) = r;
    }
}

// ---------------- fusion 1x1 conv (unchanged) ----------------
__global__ __launch_bounds__(256) void conv1x1_tiled(const float* __restrict__ comb,
                                                     const float* __restrict__ fus_wt,
                                                     const float* __restrict__ bias,
                                                     float* __restrict__ out) {
    int gid = blockIdx.x * 256 + threadIdx.x;
    int b = gid >> 14;
    int pp = gid & (HW - 1);
    const float* ip = comb + b * (256 * HW) + pp;
    float acc[64];
    #pragma unroll
    for (int co = 0; co < 64; ++co) acc[co] = bias[co];
    #pragma unroll 4
    for (int ci = 0; ci < 256; ++ci) {
        float v = ip[ci * HW];
        const float* wr = fus_wt + ci * 64;
        #pragma unroll
        for (int co = 0; co < 64; ++co) acc[co] = fmaf(v, wr[co], acc[co]);
    }
    float* op = out + b * (64 * HW) + pp;
    #pragma unroll
    for (int co = 0; co < 64; ++co) op[co * HW] = acc[co];
}

extern "C" void kernel_launch(void* const* d_in, const int* in_sizes, int n_in,
                              void* d_out, int out_size, void* d_ws, size_t ws_size,
                              hipStream_t stream) {
    const float* R      = (const float*)d_in[0];
    const float* off_w1 = (const float*)d_in[1];
    const float* off_b1 = (const float*)d_in[2];
    const float* off_w2 = (const float*)d_in[3];
    const float* off_b2 = (const float*)d_in[4];
    const float* w_sub[4] = {(const float*)d_in[5], (const float*)d_in[7],
                             (const float*)d_in[9], (const float*)d_in[11]};
    const float* b_sub[4] = {(const float*)d_in[6], (const float*)d_in[8],
                             (const float*)d_in[10], (const float*)d_in[12]};
    const float* ln_w   = (const float*)d_in[13];
    const float* ln_b   = (const float*)d_in[14];
    const float* ffn_w1 = (const float*)d_in[15];
    const float* ffn_b1 = (const float*)d_in[16];
    const float* ffn_w2 = (const float*)d_in[17];
    const float* ffn_b2 = (const float*)d_in[18];
    const float* fus_w  = (const float*)d_in[19];
    const float* fus_b  = (const float*)d_in[20];

    float* ws      = (float*)d_ws;
    float* comb    = ws;                         // [4,256,128,128] = 16,777,216
    float* o1      = ws + 16777216;              // [4,32,256,256]  =  8,388,608
    float* Zb      = ws + 16777216;              // [4,64,128,128] (after o1 dead)
    float* zbuf    = ws + 20971520;              // [4,64,128,128]  =  4,194,304
    float* disp    = ws + 25165824;              // [4,6,128,128]   =    393,216
    float* fus_wt  = ws + 25559040;              // 16,384
    float* wt_sub  = ws + 25575424;              // 147,456
    float* wt_off1 = ws + 25722880;              // 18,432
    float* w4_off2 = ws + 25741312;              // 3,072
    unsigned short* w1b  = (unsigned short*)(ws + 25744384);  // 16,384 bf16
    unsigned short* w2tb = (unsigned short*)(ws + 25752576);  // 16,384 bf16
    float* zf      = Zb;

    prep_weights<<<852, 256, 0, stream>>>(ffn_w1, w1b, ffn_w2, w2tb, fus_w, fus_wt,
                                          w_sub[0], w_sub[1], w_sub[2], w_sub[3], wt_sub,
                                          off_w1, wt_off1, off_w2, w4_off2);
    dwt_kernel<<<16384, 256, 0, stream>>>(R, comb);
    conv3x3_tiled<64, 32, 256, 256, true><<<1024, 256, 0, stream>>>(
        R, wt_off1, off_b1, o1, 64 * 65536, 32 * 65536);
    conv2_pool_tiled<<<256, 256, 0, stream>>>(o1, w4_off2, off_b2, disp);

    for (int s = 0; s < 4; ++s) {
        const float* convin;
        int in_bs;
        if (s == 0) { convin = comb; in_bs = 256 * HW; }
        else {
            deform_kernel<<<256, 256, 0, stream>>>(comb + s * 64 * HW, 256 * HW,
                                                   disp, 2 * (s - 1), Zb);
            convin = Zb; in_bs = 64 * HW;
        }
        conv3x3_tiled<64, 64, 128, 128, false><<<256, 256, 0, stream>>>(
            convin, wt_sub + s * 36864, b_sub[s], zbuf, in_bs, 64 * HW);
        ln_ffn_mfma<<<1024, 256, 0, stream>>>(zbuf, 64 * HW, comb + s * 64 * HW, 256 * HW,
                                              ln_w, ln_b, w1b, ffn_b1, w2tb, ffn_b2);
    }

    conv1x1_tiled<<<256, 256, 0, stream>>>(comb, fus_wt, fus_b, zf);
    ln_ffn_mfma<<<1024, 256, 0, stream>>>(zf, 64 * HW, (float*)d_out, 64 * HW,
                                          ln_w, ln_b, w1b, ffn_b1, w2tb, ffn_b2);
}

// Round 5
// 1036.837 us; speedup vs baseline: 7.1855x; 2.1675x over previous
//
#include <hip/hip_runtime.h>
#include <math.h>

#define HW 16384   // 128*128

typedef __attribute__((ext_vector_type(8))) short short8;
typedef __attribute__((ext_vector_type(4))) float f32x4;
typedef __attribute__((ext_vector_type(4))) unsigned int u32x4;
typedef __attribute__((ext_vector_type(2))) unsigned int u32x2;

union V4S8 { u32x4 u; short8 s; };

__device__ __forceinline__ float gelu_exact(float x) {
    return 0.5f * x * (1.0f + erff(x * 0.70710678118654752f));
}

__device__ __forceinline__ unsigned short f2bf(float x) {
    unsigned int u = __float_as_uint(x);
    u = (u + 0x7FFFu + ((u >> 16) & 1u)) >> 16;
    return (unsigned short)u;
}
__device__ __forceinline__ unsigned int pack2bf(float lo, float hi) {
    return (unsigned int)f2bf(lo) | ((unsigned int)f2bf(hi) << 16);
}
__device__ __forceinline__ float bf2f(unsigned short s) {
    unsigned int u = ((unsigned int)s) << 16;
    return __uint_as_float(u);
}

// ---------------- weight prep ----------------
// w1b  bf16 [256 h][64 c] = ffn_w1^T
// w2tb bf16 [64 co][256 h] = ffn_w2^T
// fus_wt fp32 [256 ci][64 co]
// wb_sub bf16 [4 s][9 tap][64 co][64 ci]
// wb_off1 hi/lo bf16 [9 tap][32 co][64 ci]   (split precision)
// w4_off2 fp32 [32 ci][16 uv][6 co] pooled
__global__ __launch_bounds__(256) void prep_weights(
        const float* __restrict__ ffn_w1, unsigned short* __restrict__ w1b,
        const float* __restrict__ ffn_w2, unsigned short* __restrict__ w2tb,
        const float* __restrict__ fus_w,  float* __restrict__ fus_wt,
        const float* __restrict__ w_ll, const float* __restrict__ w_lh,
        const float* __restrict__ w_hl, const float* __restrict__ w_hh,
        unsigned short* __restrict__ wb_sub,
        const float* __restrict__ off_w1, unsigned short* __restrict__ wb_off1,
        unsigned short* __restrict__ wb_off1_lo,
        const float* __restrict__ off_w2, float* __restrict__ w4_off2) {
    int gid = blockIdx.x * 256 + threadIdx.x;
    if (gid < 16384) {
        int h = gid >> 6, c = gid & 63;
        w1b[gid] = f2bf(ffn_w1[c * 256 + h]);
    } else if (gid < 32768) {
        int t = gid - 16384;
        int co = t >> 8, h = t & 255;
        w2tb[t] = f2bf(ffn_w2[h * 64 + co]);
    } else if (gid < 49152) {
        int t = gid - 32768;
        int co = t >> 8, ci = t & 255;
        fus_wt[ci * 64 + co] = fus_w[co * 256 + ci];
    } else if (gid < 196608) {
        int t = gid - 49152;
        int s = t / 36864, r = t % 36864;
        int ci = r & 63, co = (r >> 6) & 63, tap = r >> 12;
        const float* w = (s == 0) ? w_ll : (s == 1) ? w_lh : (s == 2) ? w_hl : w_hh;
        wb_sub[t] = f2bf(w[co * 576 + ci * 9 + tap]);
    } else if (gid < 215040) {
        int t = gid - 196608;
        int ci = t & 63, co = (t >> 6) & 31, tap = t >> 11;
        float w = off_w1[co * 576 + ci * 9 + tap];
        unsigned short hi = f2bf(w);
        wb_off1[t] = hi;
        wb_off1_lo[t] = f2bf(w - bf2f(hi));
    } else if (gid < 218112) {
        int t = gid - 215040;
        int co = t % 6, q = t / 6;
        int v = q & 3, u = (q >> 2) & 3, ci = q >> 4;
        float sum = 0.0f;
        #pragma unroll
        for (int r = 0; r < 2; ++r)
            #pragma unroll
            for (int s2 = 0; s2 < 2; ++s2) {
                int du = u - r, dv = v - s2;
                if (du >= 0 && du < 3 && dv >= 0 && dv < 3)
                    sum += off_w2[co * 288 + ci * 9 + du * 3 + dv];
            }
        w4_off2[ci * 96 + (u * 4 + v) * 6 + co] = 0.25f * sum;
    }
}

// ---------------- DWT: ll -> ll_p, hb -> comb slices 64..255 ----------------
__global__ __launch_bounds__(256) void dwt_kernel(const float* __restrict__ R,
                                                  float* __restrict__ ll_p,
                                                  float* __restrict__ comb) {
    int gid = blockIdx.x * 256 + threadIdx.x;
    int j = gid & 127;
    int i = (gid >> 7) & 127;
    int c = (gid >> 14) & 63;
    int b = gid >> 20;
    const float* base = R + ((b * 64 + c) * 256 + 2 * i) * 256 + 2 * j;
    float a = base[0], bb = base[1];
    float cc = base[256], dd = base[257];
    int pix = i * 128 + j;
    ll_p[(b * 64 + c) * HW + pix] = (a + bb + cc + dd) * 0.5f;
    float* o = comb + b * (256 * HW) + c * HW + pix;
    o[64 * HW]  = (cc + dd - a - bb) * 0.5f;
    o[128 * HW] = (bb - a + dd - cc) * 0.5f;
    o[192 * HW] = (a - bb - cc + dd) * 0.5f;
}

// ---------------- offset conv 64->32, SPLIT-PRECISION bf16 MFMA (~fp32 accurate) ----------------
// acc += Whi*Xhi + Whi*Xlo + Wlo*Xhi ; grid 1024 = [b 4][ty 16][tx 16]
__global__ __launch_bounds__(256) void conv_off_split(const float* __restrict__ R,
                                                      const unsigned short* __restrict__ wh, // [9][32][64]
                                                      const unsigned short* __restrict__ wl, // [9][32][64]
                                                      const float* __restrict__ bc,
                                                      float* __restrict__ o1) {
    __shared__ __align__(16) unsigned short stgh[324 * 72];
    __shared__ __align__(16) unsigned short stgl[324 * 72];
    int tid = threadIdx.x;
    int w = tid >> 6, lane = tid & 63, q = lane >> 4, m = lane & 15;
    int tx = blockIdx.x & 15, ty = (blockIdx.x >> 4) & 15, b = blockIdx.x >> 8;
    int x0 = tx * 16, y0 = ty * 16;
    const float* inb = R + (size_t)b * (64 * 65536);

    for (int e = tid; e < 324 * 64; e += 256) {
        int ch = e / 324;
        int p_ = e - ch * 324;
        int row = p_ / 18, col = p_ - row * 18;
        int gy = y0 - 1 + row, gx = x0 - 1 + col;
        float v = 0.0f;
        if ((unsigned)gy < 256u && (unsigned)gx < 256u)
            v = inb[ch * 65536 + gy * 256 + gx];
        unsigned short hi = f2bf(v);
        stgh[p_ * 72 + ch] = hi;
        stgl[p_ * 72 + ch] = f2bf(v - bf2f(hi));
    }
    __syncthreads();

    f32x4 acc[4][2];
    #pragma unroll
    for (int pt = 0; pt < 4; ++pt)
        #pragma unroll
        for (int nt = 0; nt < 2; ++nt) {
            float bv = bc[nt * 16 + m];
            acc[pt][nt] = (f32x4){bv, bv, bv, bv};
        }

    for (int tap = 0; tap < 9; ++tap) {
        int ty_ = tap / 3, tx_ = tap - 3 * ty_;
        #pragma unroll
        for (int kc = 0; kc < 2; ++kc) {
            V4S8 bh0, bh1, bl0, bl1;
            bh0.u = *(const u32x4*)(wh + (tap * 32 + m) * 64 + kc * 32 + q * 8);
            bh1.u = *(const u32x4*)(wh + (tap * 32 + 16 + m) * 64 + kc * 32 + q * 8);
            bl0.u = *(const u32x4*)(wl + (tap * 32 + m) * 64 + kc * 32 + q * 8);
            bl1.u = *(const u32x4*)(wl + (tap * 32 + 16 + m) * 64 + kc * 32 + q * 8);
            #pragma unroll
            for (int pt = 0; pt < 4; ++pt) {
                int off = ((w * 4 + pt + ty_) * 18 + m + tx_) * 72 + kc * 32 + q * 8;
                V4S8 ah, al;
                ah.u = *(const u32x4*)(stgh + off);
                al.u = *(const u32x4*)(stgl + off);
                acc[pt][0] = __builtin_amdgcn_mfma_f32_16x16x32_bf16(ah.s, bh0.s, acc[pt][0], 0, 0, 0);
                acc[pt][1] = __builtin_amdgcn_mfma_f32_16x16x32_bf16(ah.s, bh1.s, acc[pt][1], 0, 0, 0);
                acc[pt][0] = __builtin_amdgcn_mfma_f32_16x16x32_bf16(al.s, bh0.s, acc[pt][0], 0, 0, 0);
                acc[pt][1] = __builtin_amdgcn_mfma_f32_16x16x32_bf16(al.s, bh1.s, acc[pt][1], 0, 0, 0);
                acc[pt][0] = __builtin_amdgcn_mfma_f32_16x16x32_bf16(ah.s, bl0.s, acc[pt][0], 0, 0, 0);
                acc[pt][1] = __builtin_amdgcn_mfma_f32_16x16x32_bf16(ah.s, bl1.s, acc[pt][1], 0, 0, 0);
            }
        }
    }

    float* ob = o1 + (size_t)b * (32 * 65536);
    #pragma unroll
    for (int pt = 0; pt < 4; ++pt) {
        int py = y0 + w * 4 + pt;
        #pragma unroll
        for (int nt = 0; nt < 2; ++nt) {
            int co = nt * 16 + m;
            f32x4 v;
            #pragma unroll
            for (int k = 0; k < 4; ++k) v[k] = gelu_exact(acc[pt][nt][k]);
            *(f32x4*)(ob + co * 65536 + py * 256 + x0 + q * 4) = v;
        }
    }
}

// ---------------- conv2 + pool + tanh (unchanged, fp32) ----------------
__global__ __launch_bounds__(256) void conv2_pool_tiled(const float* __restrict__ o1,
                                                        const float* __restrict__ w4,
                                                        const float* __restrict__ bias,
                                                        float* __restrict__ disp) {
    constexpr int CH = 2;
    __shared__ float tile[CH * 1156];
    int tid = threadIdx.x;
    int bx = blockIdx.x & 7;
    int by = (blockIdx.x >> 3) & 7;
    int b  = blockIdx.x >> 6;
    int lx = tid & 15, ly = tid >> 4;
    int i = by * 16 + ly, j = bx * 16 + lx;
    int gy0 = by * 32 - 1, gx0 = bx * 32 - 1;
    float acc[6];
    #pragma unroll
    for (int co = 0; co < 6; ++co) acc[co] = 0.0f;
    const float* ip = o1 + b * (32 * 65536);
    for (int ci0 = 0; ci0 < 32; ci0 += CH) {
        for (int idx = tid; idx < CH * 1156; idx += 256) {
            int p = idx / 1156, r = idx % 1156;
            int ty = r / 34, tx = r % 34;
            int gy = gy0 + ty, gx = gx0 + tx;
            float v = 0.0f;
            if ((unsigned)gy < 256u && (unsigned)gx < 256u)
                v = ip[(ci0 + p) * 65536 + gy * 256 + gx];
            tile[idx] = v;
        }
        __syncthreads();
        #pragma unroll
        for (int p = 0; p < CH; ++p) {
            const float* wrow = w4 + (ci0 + p) * 96;
            const float* base = tile + p * 1156 + (2 * ly) * 34 + 2 * lx;
            #pragma unroll
            for (int u = 0; u < 4; ++u)
                #pragma unroll
                for (int v = 0; v < 4; ++v) {
                    float val = base[u * 34 + v];
                    const float* wr = wrow + (u * 4 + v) * 6;
                    #pragma unroll
                    for (int co = 0; co < 6; ++co)
                        acc[co] = fmaf(val, wr[co], acc[co]);
                }
        }
        __syncthreads();
    }
    #pragma unroll
    for (int co = 0; co < 6; ++co) {
        float pooled = acc[co] + bias[co];
        disp[b * (6 * HW) + co * HW + i * 128 + j] = tanhf(pooled) * 0.25f;
    }
}

// ---------------- deform (unchanged) ----------------
__global__ __launch_bounds__(256) void deform_kernel(const float* __restrict__ sub, int sub_bstride,
                                                     const float* __restrict__ disp, int doff,
                                                     float* __restrict__ Z) {
    int gid = blockIdx.x * 256 + threadIdx.x;
    int j = gid & 127;
    int i = (gid >> 7) & 127;
    int b = gid >> 14;
    const float* dp = disp + b * (6 * HW) + doff * HW + (i * 128 + j);
    float dx = dp[0];
    float dy = dp[HW];
    float gx = fmaf((float)j, 2.0f / 127.0f, -1.0f) + dx;
    float gy = fmaf((float)i, 2.0f / 127.0f, -1.0f) + dy;
    float ix = (gx + 1.0f) * 0.5f * 127.0f;
    float iy = (gy + 1.0f) * 0.5f * 127.0f;
    ix = fabsf(ix); ix = fmodf(ix, 254.0f); if (ix > 127.0f) ix = 254.0f - ix;
    iy = fabsf(iy); iy = fmodf(iy, 254.0f); if (iy > 127.0f) iy = 254.0f - iy;
    float x0f = floorf(ix), y0f = floorf(iy);
    float wx = ix - x0f, wy = iy - y0f;
    int x0 = min(max((int)x0f, 0), 127);
    int x1 = min(x0 + 1, 127);
    int y0 = min(max((int)y0f, 0), 127);
    int y1 = min(y0 + 1, 127);
    float w00 = (1.0f - wx) * (1.0f - wy), w01 = wx * (1.0f - wy);
    float w10 = (1.0f - wx) * wy,          w11 = wx * wy;
    int o00 = y0 * 128 + x0, o01 = y0 * 128 + x1;
    int o10 = y1 * 128 + x0, o11 = y1 * 128 + x1;
    const float* sp = sub + b * sub_bstride;
    float* zp = Z + b * (64 * HW) + i * 128 + j;
    for (int c = 0; c < 64; ++c) {
        const float* pl = sp + c * HW;
        zp[c * HW] = w00 * pl[o00] + w01 * pl[o01] + w10 * pl[o10] + w11 * pl[o11];
    }
}

// ---------------- FUSED conv3x3(64->64) + LN + FFN + residual, all MFMA ----------------
__global__ __launch_bounds__(256) void conv_ln_ffn_mfma(
        const float* __restrict__ in,            // [4][64][HW] planar fp32
        const unsigned short* __restrict__ wc,   // [9][64][64] bf16
        const float* __restrict__ bc,            // [64]
        float* __restrict__ fout,                // comb + s*64*HW, b-stride 256*HW
        const float* __restrict__ lnw, const float* __restrict__ lnb,
        const unsigned short* __restrict__ w1b,  // [256][64] bf16
        const float* __restrict__ b1,
        const unsigned short* __restrict__ w2tb, // [64][256] bf16
        const float* __restrict__ b2) {
    __shared__ __align__(16) unsigned short stg[324 * 72];   // staging, reused as Hs (4*4224)
    __shared__ __align__(16) unsigned short znS[4][64 * 72]; // per-wave zn bf16 [px][ci]
    int tid = threadIdx.x;
    int w = tid >> 6, lane = tid & 63, q = lane >> 4, m = lane & 15;
    int bx = blockIdx.x & 7, by = (blockIdx.x >> 3) & 7, b = blockIdx.x >> 6;
    int x0 = bx * 16, y0 = by * 16;
    const float* inb = in + (size_t)b * (64 * HW);

    for (int e = tid; e < 324 * 64; e += 256) {
        int ch = e / 324;
        int p_ = e - ch * 324;
        int row = p_ / 18, col = p_ - row * 18;
        int gy = y0 - 1 + row, gx = x0 - 1 + col;
        float v = 0.0f;
        if ((unsigned)gy < 128u && (unsigned)gx < 128u)
            v = inb[ch * HW + gy * 128 + gx];
        stg[p_ * 72 + ch] = f2bf(v);
    }
    __syncthreads();

    f32x4 acc[4][4];
    #pragma unroll
    for (int pt = 0; pt < 4; ++pt)
        #pragma unroll
        for (int nt = 0; nt < 4; ++nt) {
            float bv = bc[nt * 16 + m];
            acc[pt][nt] = (f32x4){bv, bv, bv, bv};
        }

    for (int tap = 0; tap < 9; ++tap) {
        int ty_ = tap / 3, tx_ = tap - 3 * ty_;
        #pragma unroll
        for (int kc = 0; kc < 2; ++kc) {
            V4S8 bf[4];
            #pragma unroll
            for (int nt = 0; nt < 4; ++nt)
                bf[nt].u = *(const u32x4*)(wc + (tap * 64 + nt * 16 + m) * 64 + kc * 32 + q * 8);
            #pragma unroll
            for (int pt = 0; pt < 4; ++pt) {
                V4S8 af;
                af.u = *(const u32x4*)(stg + ((w * 4 + pt + ty_) * 18 + m + tx_) * 72 + kc * 32 + q * 8);
                #pragma unroll
                for (int nt = 0; nt < 4; ++nt)
                    acc[pt][nt] = __builtin_amdgcn_mfma_f32_16x16x32_bf16(af.s, bf[nt].s, acc[pt][nt], 0, 0, 0);
            }
        }
    }

    f32x4 sv[4], ssv[4];
    #pragma unroll
    for (int pt = 0; pt < 4; ++pt) {
        f32x4 s_ = acc[pt][0], ss_;
        #pragma unroll
        for (int k = 0; k < 4; ++k) ss_[k] = acc[pt][0][k] * acc[pt][0][k];
        #pragma unroll
        for (int nt = 1; nt < 4; ++nt)
            #pragma unroll
            for (int k = 0; k < 4; ++k) {
                s_[k] += acc[pt][nt][k];
                ss_[k] = fmaf(acc[pt][nt][k], acc[pt][nt][k], ss_[k]);
            }
        sv[pt] = s_; ssv[pt] = ss_;
    }
    #pragma unroll
    for (int msk = 1; msk < 16; msk <<= 1)
        #pragma unroll
        for (int pt = 0; pt < 4; ++pt)
            #pragma unroll
            for (int k = 0; k < 4; ++k) {
                sv[pt][k]  += __shfl_xor(sv[pt][k],  msk);
                ssv[pt][k] += __shfl_xor(ssv[pt][k], msk);
            }

    float lwv[4], lbv[4];
    #pragma unroll
    for (int nt = 0; nt < 4; ++nt) { lwv[nt] = lnw[nt * 16 + m]; lbv[nt] = lnb[nt * 16 + m]; }
    unsigned short* zw = &znS[w][0];
    #pragma unroll
    for (int pt = 0; pt < 4; ++pt) {
        f32x4 mu, rstd;
        #pragma unroll
        for (int k = 0; k < 4; ++k) {
            mu[k] = sv[pt][k] * (1.0f / 64.0f);
            float var = ssv[pt][k] * (1.0f / 64.0f) - mu[k] * mu[k];
            rstd[k] = rsqrtf(var + 1e-5f);
        }
        #pragma unroll
        for (int nt = 0; nt < 4; ++nt)
            #pragma unroll
            for (int k = 0; k < 4; ++k) {
                float zn = (acc[pt][nt][k] - mu[k]) * rstd[k] * lwv[nt] + lbv[nt];
                zw[(pt * 16 + q * 4 + k) * 72 + nt * 16 + m] = f2bf(zn);
            }
    }
    __syncthreads();

    unsigned short* hp = stg + w * 4224;
    float b2v[4];
    #pragma unroll
    for (int nt = 0; nt < 4; ++nt) b2v[nt] = b2[nt * 16 + m];
    #pragma unroll
    for (int g = 0; g < 4; ++g) {
        V4S8 zn0, zn1;
        zn0.u = *(const u32x4*)(zw + (g * 16 + m) * 72 + q * 8);
        zn1.u = *(const u32x4*)(zw + (g * 16 + m) * 72 + 32 + q * 8);
        f32x4 Ht[16];
        #pragma unroll
        for (int ht = 0; ht < 16; ++ht) {
            f32x4 d = {0.0f, 0.0f, 0.0f, 0.0f};
            V4S8 a0, a1;
            a0.u = *(const u32x4*)(w1b + (ht * 16 + m) * 64 + q * 8);
            a1.u = *(const u32x4*)(w1b + (ht * 16 + m) * 64 + 32 + q * 8);
            d = __builtin_amdgcn_mfma_f32_16x16x32_bf16(a0.s, zn0.s, d, 0, 0, 0);
            d = __builtin_amdgcn_mfma_f32_16x16x32_bf16(a1.s, zn1.s, d, 0, 0, 0);
            Ht[ht] = d;
        }
        #pragma unroll
        for (int ht = 0; ht < 16; ++ht) {
            const f32x4 bv = *(const f32x4*)(b1 + ht * 16 + q * 4);
            u32x2 pk;
            pk[0] = pack2bf(gelu_exact(Ht[ht][0] + bv[0]), gelu_exact(Ht[ht][1] + bv[1]));
            pk[1] = pack2bf(gelu_exact(Ht[ht][2] + bv[2]), gelu_exact(Ht[ht][3] + bv[3]));
            *(u32x2*)(hp + m * 264 + ht * 16 + q * 4) = pk;
        }
        f32x4 F[4];
        #pragma unroll
        for (int nt = 0; nt < 4; ++nt) F[nt] = (f32x4){0.0f, 0.0f, 0.0f, 0.0f};
        #pragma unroll
        for (int kt = 0; kt < 8; ++kt) {
            V4S8 af;
            af.u = *(const u32x4*)(hp + m * 264 + kt * 32 + q * 8);
            #pragma unroll
            for (int nt = 0; nt < 4; ++nt) {
                V4S8 bf_;
                bf_.u = *(const u32x4*)(w2tb + (nt * 16 + m) * 256 + kt * 32 + q * 8);
                F[nt] = __builtin_amdgcn_mfma_f32_16x16x32_bf16(af.s, bf_.s, F[nt], 0, 0, 0);
            }
        }
        int py = y0 + w * 4 + g;
        float* ob = fout + (size_t)b * (256 * HW) + py * 128 + x0 + q * 4;
        #pragma unroll
        for (int nt = 0; nt < 4; ++nt) {
            int co = nt * 16 + m;
            f32x4 r_;
            #pragma unroll
            for (int k = 0; k < 4; ++k) r_[k] = acc[g][nt][k] + F[nt][k] + b2v[nt];
            *(f32x4*)(ob + co * HW) = r_;
        }
    }
}

// ---------------- fusion 1x1 conv (unchanged) ----------------
__global__ __launch_bounds__(256) void conv1x1_tiled(const float* __restrict__ comb,
                                                     const float* __restrict__ fus_wt,
                                                     const float* __restrict__ bias,
                                                     float* __restrict__ out) {
    int gid = blockIdx.x * 256 + threadIdx.x;
    int b = gid >> 14;
    int pp = gid & (HW - 1);
    const float* ip = comb + b * (256 * HW) + pp;
    float acc[64];
    #pragma unroll
    for (int co = 0; co < 64; ++co) acc[co] = bias[co];
    #pragma unroll 4
    for (int ci = 0; ci < 256; ++ci) {
        float v = ip[ci * HW];
        const float* wr = fus_wt + ci * 64;
        #pragma unroll
        for (int co = 0; co < 64; ++co) acc[co] = fmaf(v, wr[co], acc[co]);
    }
    float* op = out + b * (64 * HW) + pp;
    #pragma unroll
    for (int co = 0; co < 64; ++co) op[co * HW] = acc[co];
}

// ---------------- LN + FFN via MFMA (final stage, unchanged) ----------------
__global__ __launch_bounds__(256) void ln_ffn_mfma(
        const float* __restrict__ zin, int in_bstride,
        float* __restrict__ out, int out_bstride,
        const float* __restrict__ lnw, const float* __restrict__ lnb,
        const unsigned short* __restrict__ w1b,
        const float* __restrict__ b1,
        const unsigned short* __restrict__ w2tb,
        const float* __restrict__ b2) {
    __shared__ __align__(16) unsigned short Hs[4][16 * 264];
    int tid = threadIdx.x;
    int w = tid >> 6, lane = tid & 63;
    int q = lane >> 4, m = lane & 15;
    int gidpx = blockIdx.x * 64 + w * 16;
    int b = gidpx >> 14;
    int pp0 = gidpx & (HW - 1);
    const float* zb = zin + (size_t)b * in_bstride;
    int p = pp0 + m;
    int clo = q * 8;

    float zv[16];
    #pragma unroll
    for (int i = 0; i < 8; ++i) zv[i] = zb[(clo + i) * HW + p];
    #pragma unroll
    for (int i = 0; i < 8; ++i) zv[8 + i] = zb[(32 + clo + i) * HW + p];
    float s = 0.0f, ss = 0.0f;
    #pragma unroll
    for (int i = 0; i < 16; ++i) { s += zv[i]; ss = fmaf(zv[i], zv[i], ss); }
    s  += __shfl_xor(s, 16);  s  += __shfl_xor(s, 32);
    ss += __shfl_xor(ss, 16); ss += __shfl_xor(ss, 32);
    float mu = s * (1.0f / 64.0f);
    float var = ss * (1.0f / 64.0f) - mu * mu;
    float rstd = rsqrtf(var + 1e-5f);
    short8 znf0, znf1;
    #pragma unroll
    for (int i = 0; i < 8; ++i) {
        float g = (zv[i] - mu) * rstd * lnw[clo + i] + lnb[clo + i];
        znf0[i] = (short)f2bf(g);
        float g2 = (zv[8 + i] - mu) * rstd * lnw[32 + clo + i] + lnb[32 + clo + i];
        znf1[i] = (short)f2bf(g2);
    }

    f32x4 Ht[16];
    #pragma unroll
    for (int ht = 0; ht < 16; ++ht) {
        f32x4 d = {0.0f, 0.0f, 0.0f, 0.0f};
        V4S8 a0, a1;
        a0.u = *(const u32x4*)(w1b + (ht * 16 + m) * 64 + q * 8);
        a1.u = *(const u32x4*)(w1b + (ht * 16 + m) * 64 + 32 + q * 8);
        d = __builtin_amdgcn_mfma_f32_16x16x32_bf16(a0.s, znf0, d, 0, 0, 0);
        d = __builtin_amdgcn_mfma_f32_16x16x32_bf16(a1.s, znf1, d, 0, 0, 0);
        Ht[ht] = d;
    }

    unsigned short* hp = &Hs[w][0];
    #pragma unroll
    for (int ht = 0; ht < 16; ++ht) {
        const f32x4 bv = *(const f32x4*)(b1 + ht * 16 + q * 4);
        u32x2 pk;
        pk[0] = pack2bf(gelu_exact(Ht[ht][0] + bv[0]), gelu_exact(Ht[ht][1] + bv[1]));
        pk[1] = pack2bf(gelu_exact(Ht[ht][2] + bv[2]), gelu_exact(Ht[ht][3] + bv[3]));
        *(u32x2*)(hp + m * 264 + ht * 16 + q * 4) = pk;
    }
    __syncthreads();

    f32x4 F[4];
    #pragma unroll
    for (int nt = 0; nt < 4; ++nt) F[nt] = (f32x4){0.0f, 0.0f, 0.0f, 0.0f};
    #pragma unroll
    for (int kt = 0; kt < 8; ++kt) {
        V4S8 af;
        af.u = *(const u32x4*)(hp + m * 264 + kt * 32 + q * 8);
        #pragma unroll
        for (int nt = 0; nt < 4; ++nt) {
            V4S8 bf_;
            bf_.u = *(const u32x4*)(w2tb + (nt * 16 + m) * 256 + kt * 32 + q * 8);
            F[nt] = __builtin_amdgcn_mfma_f32_16x16x32_bf16(af.s, bf_.s, F[nt], 0, 0, 0);
        }
    }

    float* ob = out + (size_t)b * out_bstride;
    #pragma unroll
    for (int nt = 0; nt < 4; ++nt) {
        int co = nt * 16 + m;
        const f32x4 zr = *(const f32x4*)(zb + co * HW + pp0 + q * 4);
        float bias = b2[co];
        f32x4 r;
        #pragma unroll
        for (int k = 0; k < 4; ++k) r[k] = zr[k] + F[nt][k] + bias;
        *(f32x4*)(ob + co * HW + pp0 + q * 4) = r;
    }
}

extern "C" void kernel_launch(void* const* d_in, const int* in_sizes, int n_in,
                              void* d_out, int out_size, void* d_ws, size_t ws_size,
                              hipStream_t stream) {
    const float* R      = (const float*)d_in[0];
    const float* off_w1 = (const float*)d_in[1];
    const float* off_b1 = (const float*)d_in[2];
    const float* off_w2 = (const float*)d_in[3];
    const float* off_b2 = (const float*)d_in[4];
    const float* w_sub[4] = {(const float*)d_in[5], (const float*)d_in[7],
                             (const float*)d_in[9], (const float*)d_in[11]};
    const float* b_sub[4] = {(const float*)d_in[6], (const float*)d_in[8],
                             (const float*)d_in[10], (const float*)d_in[12]};
    const float* ln_w   = (const float*)d_in[13];
    const float* ln_b   = (const float*)d_in[14];
    const float* ffn_w1 = (const float*)d_in[15];
    const float* ffn_b1 = (const float*)d_in[16];
    const float* ffn_w2 = (const float*)d_in[17];
    const float* ffn_b2 = (const float*)d_in[18];
    const float* fus_w  = (const float*)d_in[19];
    const float* fus_b  = (const float*)d_in[20];

    float* ws      = (float*)d_ws;
    float* comb    = ws;                         // [4,256,128,128] = 16,777,216
    float* o1      = ws + 16777216;              // [4,32,256,256]  =  8,388,608 (dead after pool)
    float* ll_p    = ws + 16777216;              // [4,64,128,128] (o1 region, after o1 dead)
    float* Zb      = ws + 20971520;              // [4,64,128,128]  =  4,194,304
    float* zf      = ws + 20971520;              // alias Z (dead by conv1x1)
    float* disp    = ws + 25165824;              //    393,216
    float* fus_wt  = ws + 25559040;              //     16,384
    float* w4_off2 = ws + 25575424;              //      3,072
    unsigned short* w1b        = (unsigned short*)(ws + 25578496);  // 16,384 s
    unsigned short* w2tb       = (unsigned short*)(ws + 25586688);  // 16,384 s
    unsigned short* wb_sub     = (unsigned short*)(ws + 25594880);  // 147,456 s
    unsigned short* wb_off1    = (unsigned short*)(ws + 25668608);  // 18,432 s
    unsigned short* wb_off1_lo = (unsigned short*)(ws + 25677824);  // 18,432 s
    // end: 25,687,040 floats (~102.75 MB)

    prep_weights<<<852, 256, 0, stream>>>(ffn_w1, w1b, ffn_w2, w2tb, fus_w, fus_wt,
                                          w_sub[0], w_sub[1], w_sub[2], w_sub[3], wb_sub,
                                          off_w1, wb_off1, wb_off1_lo, off_w2, w4_off2);
    conv_off_split<<<1024, 256, 0, stream>>>(R, wb_off1, wb_off1_lo, off_b1, o1);
    conv2_pool_tiled<<<256, 256, 0, stream>>>(o1, w4_off2, off_b2, disp);
    dwt_kernel<<<16384, 256, 0, stream>>>(R, ll_p, comb);

    for (int s = 0; s < 4; ++s) {
        const float* convin;
        if (s == 0) convin = ll_p;
        else {
            deform_kernel<<<256, 256, 0, stream>>>(comb + s * 64 * HW, 256 * HW,
                                                   disp, 2 * (s - 1), Zb);
            convin = Zb;
        }
        conv_ln_ffn_mfma<<<256, 256, 0, stream>>>(
            convin, wb_sub + s * 36864, b_sub[s], comb + s * 64 * HW,
            ln_w, ln_b, w1b, ffn_b1, w2tb, ffn_b2);
    }

    conv1x1_tiled<<<256, 256, 0, stream>>>(comb, fus_wt, fus_b, zf);
    ln_ffn_mfma<<<1024, 256, 0, stream>>>(zf, 64 * HW, (float*)d_out, 64 * HW,
                                          ln_w, ln_b, w1b, ffn_b1, w2tb, ffn_b2);
}

// Round 6
// 767.428 us; speedup vs baseline: 9.7081x; 1.3511x over previous
//
#include <hip/hip_runtime.h>
#include <math.h>

#define HW 16384   // 128*128

typedef __attribute__((ext_vector_type(8))) short short8;
typedef __attribute__((ext_vector_type(4))) float f32x4;
typedef __attribute__((ext_vector_type(4))) unsigned int u32x4;
typedef __attribute__((ext_vector_type(2))) unsigned int u32x2;

union V4S8 { u32x4 u; short8 s; };

__device__ __forceinline__ float gelu_exact(float x) {
    return 0.5f * x * (1.0f + erff(x * 0.70710678118654752f));
}
__device__ __forceinline__ unsigned short f2bf(float x) {
    unsigned int u = __float_as_uint(x);
    u = (u + 0x7FFFu + ((u >> 16) & 1u)) >> 16;
    return (unsigned short)u;
}
__device__ __forceinline__ unsigned int pack2bf(float lo, float hi) {
    return (unsigned int)f2bf(lo) | ((unsigned int)f2bf(hi) << 16);
}
__device__ __forceinline__ float bf2f(unsigned short s) {
    return __uint_as_float(((unsigned int)s) << 16);
}

// ---------------- weight prep ----------------
__global__ __launch_bounds__(256) void prep_weights(
        const float* __restrict__ ffn_w1, unsigned short* __restrict__ w1b,
        const float* __restrict__ ffn_w2, unsigned short* __restrict__ w2tb,
        const float* __restrict__ fus_w,  unsigned short* __restrict__ fus_wb,
        const float* __restrict__ w_ll, const float* __restrict__ w_lh,
        const float* __restrict__ w_hl, const float* __restrict__ w_hh,
        unsigned short* __restrict__ wb_sub,
        const float* __restrict__ off_w1, unsigned short* __restrict__ wb_off1,
        unsigned short* __restrict__ wb_off1_lo,
        const float* __restrict__ off_w2, float* __restrict__ w4_off2) {
    int gid = blockIdx.x * 256 + threadIdx.x;
    if (gid < 16384) {
        int h = gid >> 6, c = gid & 63;
        w1b[gid] = f2bf(ffn_w1[c * 256 + h]);
    } else if (gid < 32768) {
        int t = gid - 16384;
        int co = t >> 8, h = t & 255;
        w2tb[t] = f2bf(ffn_w2[h * 64 + co]);
    } else if (gid < 49152) {
        int t = gid - 32768;
        fus_wb[t] = f2bf(fus_w[t]);                 // [64 co][256 ci] native
    } else if (gid < 196608) {
        int t = gid - 49152;
        int s = t / 36864, r = t % 36864;
        int ci = r & 63, co = (r >> 6) & 63, tap = r >> 12;
        const float* w = (s == 0) ? w_ll : (s == 1) ? w_lh : (s == 2) ? w_hl : w_hh;
        wb_sub[t] = f2bf(w[co * 576 + ci * 9 + tap]);
    } else if (gid < 215040) {
        int t = gid - 196608;
        int ci = t & 63, co = (t >> 6) & 31, tap = t >> 11;
        float w = off_w1[co * 576 + ci * 9 + tap];
        unsigned short hi = f2bf(w);
        wb_off1[t] = hi;
        wb_off1_lo[t] = f2bf(w - bf2f(hi));
    } else if (gid < 218112) {
        int t = gid - 215040;
        int co = t % 6, q = t / 6;
        int v = q & 3, u = (q >> 2) & 3, ci = q >> 4;
        float sum = 0.0f;
        #pragma unroll
        for (int r = 0; r < 2; ++r)
            #pragma unroll
            for (int s2 = 0; s2 < 2; ++s2) {
                int du = u - r, dv = v - s2;
                if (du >= 0 && du < 3 && dv >= 0 && dv < 3)
                    sum += off_w2[co * 288 + ci * 9 + du * 3 + dv];
            }
        w4_off2[ci * 96 + (u * 4 + v) * 6 + co] = 0.25f * sum;
    }
}

// ---------------- DWT: R -> ll_p [4][64][HW] + hb [3][4][64][HW] ----------------
__global__ __launch_bounds__(256) void dwt_kernel(const float* __restrict__ R,
                                                  float* __restrict__ ll_p,
                                                  float* __restrict__ hb) {
    int gid = blockIdx.x * 256 + threadIdx.x;
    int j = gid & 127;
    int i = (gid >> 7) & 127;
    int c = (gid >> 14) & 63;
    int b = gid >> 20;
    const float* base = R + ((b * 64 + c) * 256 + 2 * i) * 256 + 2 * j;
    float a = base[0], bb = base[1];
    float cc = base[256], dd = base[257];
    size_t po = ((size_t)b * 64 + c) * HW + i * 128 + j;
    ll_p[po]             = (a + bb + cc + dd) * 0.5f;
    hb[po]               = (cc + dd - a - bb) * 0.5f;   // lh
    hb[4194304 + po]     = (bb - a + dd - cc) * 0.5f;   // hl
    hb[2 * 4194304 + po] = (a - bb - cc + dd) * 0.5f;   // hh
}

// ---------------- offset conv 64->32, split-precision bf16 MFMA, K-chunked LDS ----------------
__global__ __launch_bounds__(256) void conv_off_split(const float* __restrict__ R,
                                                      const unsigned short* __restrict__ wh,
                                                      const unsigned short* __restrict__ wl,
                                                      const float* __restrict__ bc,
                                                      float* __restrict__ o1) {
    __shared__ __align__(16) unsigned short sh[324 * 40];  // 25,920 B
    __shared__ __align__(16) unsigned short sl[324 * 40];  // 25,920 B
    int tid = threadIdx.x;
    int w = tid >> 6, lane = tid & 63, q = lane >> 4, m = lane & 15;
    int tx = blockIdx.x & 15, ty = (blockIdx.x >> 4) & 15, b = blockIdx.x >> 8;
    int x0 = tx * 16, y0 = ty * 16;
    const float* inb = R + (size_t)b * (64 * 65536);

    f32x4 acc[4][2];
    #pragma unroll
    for (int pt = 0; pt < 4; ++pt)
        #pragma unroll
        for (int nt = 0; nt < 2; ++nt) {
            float bv = bc[nt * 16 + m];
            acc[pt][nt] = (f32x4){bv, bv, bv, bv};
        }

    for (int kc = 0; kc < 2; ++kc) {
        for (int idx = tid; idx < 324 * 32; idx += 256) {
            int ch = idx / 324, pp = idx - ch * 324;
            int row = pp / 18, col = pp - row * 18;
            int gy = y0 - 1 + row, gx = x0 - 1 + col;
            float v = 0.0f;
            if ((unsigned)gy < 256u && (unsigned)gx < 256u)
                v = inb[(kc * 32 + ch) * 65536 + gy * 256 + gx];
            unsigned short hi = f2bf(v);
            sh[pp * 40 + ch] = hi;
            sl[pp * 40 + ch] = f2bf(v - bf2f(hi));
        }
        __syncthreads();
        for (int tap = 0; tap < 9; ++tap) {
            int ty_ = tap / 3, tx_ = tap - 3 * ty_;
            V4S8 bh0, bh1, bl0, bl1;
            bh0.u = *(const u32x4*)(wh + (tap * 32 + m) * 64 + kc * 32 + q * 8);
            bh1.u = *(const u32x4*)(wh + (tap * 32 + 16 + m) * 64 + kc * 32 + q * 8);
            bl0.u = *(const u32x4*)(wl + (tap * 32 + m) * 64 + kc * 32 + q * 8);
            bl1.u = *(const u32x4*)(wl + (tap * 32 + 16 + m) * 64 + kc * 32 + q * 8);
            #pragma unroll
            for (int pt = 0; pt < 4; ++pt) {
                int off = ((w * 4 + pt + ty_) * 18 + m + tx_) * 40 + q * 8;
                V4S8 ah, al;
                ah.u = *(const u32x4*)(sh + off);
                al.u = *(const u32x4*)(sl + off);
                acc[pt][0] = __builtin_amdgcn_mfma_f32_16x16x32_bf16(ah.s, bh0.s, acc[pt][0], 0, 0, 0);
                acc[pt][1] = __builtin_amdgcn_mfma_f32_16x16x32_bf16(ah.s, bh1.s, acc[pt][1], 0, 0, 0);
                acc[pt][0] = __builtin_amdgcn_mfma_f32_16x16x32_bf16(al.s, bh0.s, acc[pt][0], 0, 0, 0);
                acc[pt][1] = __builtin_amdgcn_mfma_f32_16x16x32_bf16(al.s, bh1.s, acc[pt][1], 0, 0, 0);
                acc[pt][0] = __builtin_amdgcn_mfma_f32_16x16x32_bf16(ah.s, bl0.s, acc[pt][0], 0, 0, 0);
                acc[pt][1] = __builtin_amdgcn_mfma_f32_16x16x32_bf16(ah.s, bl1.s, acc[pt][1], 0, 0, 0);
            }
        }
        __syncthreads();
    }

    float* ob = o1 + (size_t)b * (32 * 65536);
    #pragma unroll
    for (int pt = 0; pt < 4; ++pt) {
        int py = y0 + w * 4 + pt;
        #pragma unroll
        for (int nt = 0; nt < 2; ++nt) {
            int co = nt * 16 + m;
            f32x4 v;
            #pragma unroll
            for (int k = 0; k < 4; ++k) v[k] = gelu_exact(acc[pt][nt][k]);
            *(f32x4*)(ob + co * 65536 + py * 256 + x0 + q * 4) = v;
        }
    }
}

// ---------------- conv2 + pool + tanh (fp32) ----------------
__global__ __launch_bounds__(256) void conv2_pool_tiled(const float* __restrict__ o1,
                                                        const float* __restrict__ w4,
                                                        const float* __restrict__ bias,
                                                        float* __restrict__ disp) {
    constexpr int CH = 2;
    __shared__ float tile[CH * 1156];
    int tid = threadIdx.x;
    int bx = blockIdx.x & 7;
    int by = (blockIdx.x >> 3) & 7;
    int b  = blockIdx.x >> 6;
    int lx = tid & 15, ly = tid >> 4;
    int i = by * 16 + ly, j = bx * 16 + lx;
    int gy0 = by * 32 - 1, gx0 = bx * 32 - 1;
    float acc[6];
    #pragma unroll
    for (int co = 0; co < 6; ++co) acc[co] = 0.0f;
    const float* ip = o1 + (size_t)b * (32 * 65536);
    for (int ci0 = 0; ci0 < 32; ci0 += CH) {
        for (int idx = tid; idx < CH * 1156; idx += 256) {
            int p = idx / 1156, r = idx % 1156;
            int ty = r / 34, tx = r % 34;
            int gy = gy0 + ty, gx = gx0 + tx;
            float v = 0.0f;
            if ((unsigned)gy < 256u && (unsigned)gx < 256u)
                v = ip[(ci0 + p) * 65536 + gy * 256 + gx];
            tile[idx] = v;
        }
        __syncthreads();
        #pragma unroll
        for (int p = 0; p < CH; ++p) {
            const float* wrow = w4 + (ci0 + p) * 96;
            const float* base = tile + p * 1156 + (2 * ly) * 34 + 2 * lx;
            #pragma unroll
            for (int u = 0; u < 4; ++u)
                #pragma unroll
                for (int v = 0; v < 4; ++v) {
                    float val = base[u * 34 + v];
                    const float* wr = wrow + (u * 4 + v) * 6;
                    #pragma unroll
                    for (int co = 0; co < 6; ++co)
                        acc[co] = fmaf(val, wr[co], acc[co]);
                }
        }
        __syncthreads();
    }
    #pragma unroll
    for (int co = 0; co < 6; ++co) {
        float pooled = acc[co] + bias[co];
        disp[(size_t)b * (6 * HW) + co * HW + i * 128 + j] = tanhf(pooled) * 0.25f;
    }
}

// ---------------- FUSED deform + conv3x3 + LN + FFN for ALL 4 subbands ----------------
// grid 1024 = [tile 256][s 4]; block 256 = 4 waves. LDS 45.6 KB.
__global__ __launch_bounds__(256) void subband_fused(
        const float* __restrict__ ll_p,            // [4][64][HW]
        const float* __restrict__ hb,              // [3][4][64][HW]
        const float* __restrict__ disp,            // [4][6][HW]
        const unsigned short* __restrict__ wb_sub, // [4][9][64][64]
        const float* __restrict__ b_ll, const float* __restrict__ b_lh,
        const float* __restrict__ b_hl, const float* __restrict__ b_hh,
        unsigned short* __restrict__ fb,           // [4 s][4 b][64][HW] bf16
        const float* __restrict__ lnw, const float* __restrict__ lnb,
        const unsigned short* __restrict__ w1b, const float* __restrict__ b1,
        const unsigned short* __restrict__ w2tb, const float* __restrict__ b2) {
    __shared__ __align__(16) unsigned short stg[324 * 72];   // 46,656 B; re-carved post-conv
    int tid = threadIdx.x;
    int w = tid >> 6, lane = tid & 63, q = lane >> 4, m = lane & 15;
    int s = blockIdx.x & 3;
    int t = blockIdx.x >> 2;
    int bx = t & 7, by = (t >> 3) & 7, b = t >> 6;
    int x0 = bx * 16, y0 = by * 16;
    const unsigned short* wc = wb_sub + s * 36864;
    const float* bc = (s == 0) ? b_ll : (s == 1) ? b_lh : (s == 2) ? b_hl : b_hh;

    // --- staging: 18x18 halo x 64ch, deform fused for s>0 ---
    if (s == 0) {
        const float* inb = ll_p + (size_t)b * (64 * HW);
        for (int pp = tid; pp < 324; pp += 256) {
            int row = pp / 18, col = pp - row * 18;
            int gy = y0 - 1 + row, gx = x0 - 1 + col;
            bool ok = ((unsigned)gy < 128u) && ((unsigned)gx < 128u);
            const float* src = inb + (ok ? (gy * 128 + gx) : 0);
            #pragma unroll 8
            for (int ch = 0; ch < 64; ch += 2) {
                float v0 = ok ? src[ch * HW] : 0.0f;
                float v1 = ok ? src[(ch + 1) * HW] : 0.0f;
                *(unsigned int*)(stg + pp * 72 + ch) = pack2bf(v0, v1);
            }
        }
    } else {
        const float* sp  = hb + (size_t)((s - 1) * 4 + b) * (64 * HW);
        const float* dpb = disp + (size_t)b * (6 * HW) + (s - 1) * 2 * HW;
        for (int pp = tid; pp < 324; pp += 256) {
            int row = pp / 18, col = pp - row * 18;
            int gy = y0 - 1 + row, gx = x0 - 1 + col;
            bool ok = ((unsigned)gy < 128u) && ((unsigned)gx < 128u);
            int o00 = 0, o01 = 0, o10 = 0, o11 = 0;
            float w00 = 0, w01 = 0, w10 = 0, w11 = 0;
            if (ok) {
                int pix = gy * 128 + gx;
                float dx = dpb[pix], dy = dpb[HW + pix];
                float fx = fmaf((float)gx, 2.0f / 127.0f, -1.0f) + dx;
                float fy = fmaf((float)gy, 2.0f / 127.0f, -1.0f) + dy;
                float ix = (fx + 1.0f) * 0.5f * 127.0f;
                float iy = (fy + 1.0f) * 0.5f * 127.0f;
                ix = fabsf(ix); ix = fmodf(ix, 254.0f); if (ix > 127.0f) ix = 254.0f - ix;
                iy = fabsf(iy); iy = fmodf(iy, 254.0f); if (iy > 127.0f) iy = 254.0f - iy;
                float x0f = floorf(ix), y0f = floorf(iy);
                float wx = ix - x0f, wy = iy - y0f;
                int xa = min(max((int)x0f, 0), 127);
                int xb2 = min(xa + 1, 127);
                int ya = min(max((int)y0f, 0), 127);
                int yb2 = min(ya + 1, 127);
                w00 = (1.0f - wx) * (1.0f - wy); w01 = wx * (1.0f - wy);
                w10 = (1.0f - wx) * wy;          w11 = wx * wy;
                o00 = ya * 128 + xa;  o01 = ya * 128 + xb2;
                o10 = yb2 * 128 + xa; o11 = yb2 * 128 + xb2;
            }
            #pragma unroll 4
            for (int ch = 0; ch < 64; ch += 2) {
                const float* pl = sp + ch * HW;
                const float* pl1 = pl + HW;
                float v0 = w00 * pl[o00] + w01 * pl[o01] + w10 * pl[o10] + w11 * pl[o11];
                float v1 = w00 * pl1[o00] + w01 * pl1[o01] + w10 * pl1[o10] + w11 * pl1[o11];
                *(unsigned int*)(stg + pp * 72 + ch) = pack2bf(v0, v1);
            }
        }
    }
    __syncthreads();

    // --- conv MFMA ---
    f32x4 acc[4][4];
    #pragma unroll
    for (int pt = 0; pt < 4; ++pt)
        #pragma unroll
        for (int nt = 0; nt < 4; ++nt) {
            float bv = bc[nt * 16 + m];
            acc[pt][nt] = (f32x4){bv, bv, bv, bv};
        }
    for (int tap = 0; tap < 9; ++tap) {
        int ty_ = tap / 3, tx_ = tap - 3 * ty_;
        #pragma unroll
        for (int kc = 0; kc < 2; ++kc) {
            V4S8 bf[4];
            #pragma unroll
            for (int nt = 0; nt < 4; ++nt)
                bf[nt].u = *(const u32x4*)(wc + (tap * 64 + nt * 16 + m) * 64 + kc * 32 + q * 8);
            #pragma unroll
            for (int pt = 0; pt < 4; ++pt) {
                V4S8 af;
                af.u = *(const u32x4*)(stg + ((w * 4 + pt + ty_) * 18 + m + tx_) * 72 + kc * 32 + q * 8);
                #pragma unroll
                for (int nt = 0; nt < 4; ++nt)
                    acc[pt][nt] = __builtin_amdgcn_mfma_f32_16x16x32_bf16(af.s, bf[nt].s, acc[pt][nt], 0, 0, 0);
            }
        }
    }

    // --- LN stats (registers + shfl only) ---
    f32x4 sv[4], ssv[4];
    #pragma unroll
    for (int pt = 0; pt < 4; ++pt) {
        f32x4 s_ = acc[pt][0], ss_;
        #pragma unroll
        for (int k = 0; k < 4; ++k) ss_[k] = acc[pt][0][k] * acc[pt][0][k];
        #pragma unroll
        for (int nt = 1; nt < 4; ++nt)
            #pragma unroll
            for (int k = 0; k < 4; ++k) {
                s_[k] += acc[pt][nt][k];
                ss_[k] = fmaf(acc[pt][nt][k], acc[pt][nt][k], ss_[k]);
            }
        sv[pt] = s_; ssv[pt] = ss_;
    }
    #pragma unroll
    for (int msk = 1; msk < 16; msk <<= 1)
        #pragma unroll
        for (int pt = 0; pt < 4; ++pt)
            #pragma unroll
            for (int k = 0; k < 4; ++k) {
                sv[pt][k]  += __shfl_xor(sv[pt][k],  msk);
                ssv[pt][k] += __shfl_xor(ssv[pt][k], msk);
            }

    __syncthreads();   // all conv reads of stg done -> stg re-carved per wave

    // --- zn -> per-wave LDS region (aliases stg), then preload to regs ---
    unsigned short* zw = stg + w * 4608;   // 64 px * 72
    float lwv[4], lbv[4];
    #pragma unroll
    for (int nt = 0; nt < 4; ++nt) { lwv[nt] = lnw[nt * 16 + m]; lbv[nt] = lnb[nt * 16 + m]; }
    #pragma unroll
    for (int pt = 0; pt < 4; ++pt) {
        f32x4 mu, rstd;
        #pragma unroll
        for (int k = 0; k < 4; ++k) {
            mu[k] = sv[pt][k] * (1.0f / 64.0f);
            float var = ssv[pt][k] * (1.0f / 64.0f) - mu[k] * mu[k];
            rstd[k] = rsqrtf(var + 1e-5f);
        }
        #pragma unroll
        for (int nt = 0; nt < 4; ++nt)
            #pragma unroll
            for (int k = 0; k < 4; ++k) {
                float zn = (acc[pt][nt][k] - mu[k]) * rstd[k] * lwv[nt] + lbv[nt];
                zw[(pt * 16 + q * 4 + k) * 72 + nt * 16 + m] = f2bf(zn);
            }
    }
    u32x4 znp[4][2];
    #pragma unroll
    for (int g = 0; g < 4; ++g) {
        znp[g][0] = *(const u32x4*)(zw + (g * 16 + m) * 72 + q * 8);
        znp[g][1] = *(const u32x4*)(zw + (g * 16 + m) * 72 + 32 + q * 8);
    }

    // --- FFN per 16-px group; Hs aliases zw (wave-private, DS ops in-order) ---
    unsigned short* hp = zw;
    float b2v[4];
    #pragma unroll
    for (int nt = 0; nt < 4; ++nt) b2v[nt] = b2[nt * 16 + m];
    #pragma unroll
    for (int g = 0; g < 4; ++g) {
        V4S8 zn0, zn1;
        zn0.u = znp[g][0]; zn1.u = znp[g][1];
        f32x4 Ht[16];
        #pragma unroll
        for (int ht = 0; ht < 16; ++ht) {
            f32x4 d = {0.0f, 0.0f, 0.0f, 0.0f};
            V4S8 a0, a1;
            a0.u = *(const u32x4*)(w1b + (ht * 16 + m) * 64 + q * 8);
            a1.u = *(const u32x4*)(w1b + (ht * 16 + m) * 64 + 32 + q * 8);
            d = __builtin_amdgcn_mfma_f32_16x16x32_bf16(a0.s, zn0.s, d, 0, 0, 0);
            d = __builtin_amdgcn_mfma_f32_16x16x32_bf16(a1.s, zn1.s, d, 0, 0, 0);
            Ht[ht] = d;
        }
        #pragma unroll
        for (int ht = 0; ht < 16; ++ht) {
            const f32x4 bv = *(const f32x4*)(b1 + ht * 16 + q * 4);
            u32x2 pk;
            pk[0] = pack2bf(gelu_exact(Ht[ht][0] + bv[0]), gelu_exact(Ht[ht][1] + bv[1]));
            pk[1] = pack2bf(gelu_exact(Ht[ht][2] + bv[2]), gelu_exact(Ht[ht][3] + bv[3]));
            *(u32x2*)(hp + m * 264 + ht * 16 + q * 4) = pk;
        }
        f32x4 F[4];
        #pragma unroll
        for (int nt = 0; nt < 4; ++nt) F[nt] = (f32x4){0.0f, 0.0f, 0.0f, 0.0f};
        #pragma unroll
        for (int kt = 0; kt < 8; ++kt) {
            V4S8 af;
            af.u = *(const u32x4*)(hp + m * 264 + kt * 32 + q * 8);
            #pragma unroll
            for (int nt = 0; nt < 4; ++nt) {
                V4S8 bf_;
                bf_.u = *(const u32x4*)(w2tb + (nt * 16 + m) * 256 + kt * 32 + q * 8);
                F[nt] = __builtin_amdgcn_mfma_f32_16x16x32_bf16(af.s, bf_.s, F[nt], 0, 0, 0);
            }
        }
        int py = y0 + w * 4 + g;
        unsigned short* ob = fb + (size_t)((s * 4 + b) * 64) * HW + py * 128 + x0 + q * 4;
        #pragma unroll
        for (int nt = 0; nt < 4; ++nt) {
            int co = nt * 16 + m;
            float r0 = acc[g][nt][0] + F[nt][0] + b2v[nt];
            float r1 = acc[g][nt][1] + F[nt][1] + b2v[nt];
            float r2 = acc[g][nt][2] + F[nt][2] + b2v[nt];
            float r3 = acc[g][nt][3] + F[nt][3] + b2v[nt];
            u32x2 pk;
            pk[0] = pack2bf(r0, r1);
            pk[1] = pack2bf(r2, r3);
            *(u32x2*)(ob + (size_t)co * HW) = pk;
        }
    }
}

// ---------------- FUSED 1x1 fusion conv (K=256) + LN + FFN + residual ----------------
// grid 1024; block 256 = 4 waves x 16 px; LDS 33.8 KB -> 4 blocks/CU.
__global__ __launch_bounds__(256) void fus_ln_ffn(
        const unsigned short* __restrict__ fb,   // [4 s][4 b][64][HW] bf16
        const unsigned short* __restrict__ fwb,  // [64 co][256 ci] bf16
        const float* __restrict__ fbias,
        float* __restrict__ out,                 // [4][64][HW] fp32
        const float* __restrict__ lnw, const float* __restrict__ lnb,
        const unsigned short* __restrict__ w1b, const float* __restrict__ b1,
        const unsigned short* __restrict__ w2tb, const float* __restrict__ b2) {
    __shared__ __align__(16) unsigned short stgF[64 * 264];  // 33,792 B
    int tid = threadIdx.x;
    int w = tid >> 6, lane = tid & 63, q = lane >> 4, m = lane & 15;
    int gpx = blockIdx.x * 64;
    int b = gpx >> 14;
    int pp0 = gpx & (HW - 1);

    // stage 64 px x 256 ci (bf16 copy, coalesced u32 over px pairs)
    for (int idx = tid; idx < 8192; idx += 256) {
        int ci = idx >> 5, pxp = (idx & 31) << 1;
        int s_ = ci >> 6, c = ci & 63;
        unsigned int v = *(const unsigned int*)(fb + (size_t)((s_ * 4 + b) * 64 + c) * HW + pp0 + pxp);
        stgF[pxp * 264 + ci] = (unsigned short)v;
        stgF[(pxp + 1) * 264 + ci] = (unsigned short)(v >> 16);
    }
    __syncthreads();

    // GEMM: zf[16 px][64 co], K = 256
    f32x4 acc[4];
    #pragma unroll
    for (int nt = 0; nt < 4; ++nt) {
        float bv = fbias[nt * 16 + m];
        acc[nt] = (f32x4){bv, bv, bv, bv};
    }
    #pragma unroll
    for (int kc = 0; kc < 8; ++kc) {
        V4S8 af;
        af.u = *(const u32x4*)(stgF + (w * 16 + m) * 264 + kc * 32 + q * 8);
        #pragma unroll
        for (int nt = 0; nt < 4; ++nt) {
            V4S8 bf_;
            bf_.u = *(const u32x4*)(fwb + (nt * 16 + m) * 256 + kc * 32 + q * 8);
            acc[nt] = __builtin_amdgcn_mfma_f32_16x16x32_bf16(af.s, bf_.s, acc[nt], 0, 0, 0);
        }
    }

    // LN over 64 co
    f32x4 s_ = acc[0], ss_;
    #pragma unroll
    for (int k = 0; k < 4; ++k) ss_[k] = acc[0][k] * acc[0][k];
    #pragma unroll
    for (int nt = 1; nt < 4; ++nt)
        #pragma unroll
        for (int k = 0; k < 4; ++k) {
            s_[k] += acc[nt][k];
            ss_[k] = fmaf(acc[nt][k], acc[nt][k], ss_[k]);
        }
    #pragma unroll
    for (int msk = 1; msk < 16; msk <<= 1)
        #pragma unroll
        for (int k = 0; k < 4; ++k) {
            s_[k]  += __shfl_xor(s_[k],  msk);
            ss_[k] += __shfl_xor(ss_[k], msk);
        }
    f32x4 mu, rstd;
    #pragma unroll
    for (int k = 0; k < 4; ++k) {
        mu[k] = s_[k] * (1.0f / 64.0f);
        float var = ss_[k] * (1.0f / 64.0f) - mu[k] * mu[k];
        rstd[k] = rsqrtf(var + 1e-5f);
    }

    // zn -> wave-private region (aliases own staging rows), preload, FFN
    unsigned short* zw = stgF + w * 4224;
    float lwv[4], lbv[4];
    #pragma unroll
    for (int nt = 0; nt < 4; ++nt) { lwv[nt] = lnw[nt * 16 + m]; lbv[nt] = lnb[nt * 16 + m]; }
    #pragma unroll
    for (int nt = 0; nt < 4; ++nt)
        #pragma unroll
        for (int k = 0; k < 4; ++k) {
            float zn = (acc[nt][k] - mu[k]) * rstd[k] * lwv[nt] + lbv[nt];
            zw[(q * 4 + k) * 72 + nt * 16 + m] = f2bf(zn);
        }
    V4S8 zn0, zn1;
    zn0.u = *(const u32x4*)(zw + m * 72 + q * 8);
    zn1.u = *(const u32x4*)(zw + m * 72 + 32 + q * 8);

    unsigned short* hp = zw;
    f32x4 Ht[16];
    #pragma unroll
    for (int ht = 0; ht < 16; ++ht) {
        f32x4 d = {0.0f, 0.0f, 0.0f, 0.0f};
        V4S8 a0, a1;
        a0.u = *(const u32x4*)(w1b + (ht * 16 + m) * 64 + q * 8);
        a1.u = *(const u32x4*)(w1b + (ht * 16 + m) * 64 + 32 + q * 8);
        d = __builtin_amdgcn_mfma_f32_16x16x32_bf16(a0.s, zn0.s, d, 0, 0, 0);
        d = __builtin_amdgcn_mfma_f32_16x16x32_bf16(a1.s, zn1.s, d, 0, 0, 0);
        Ht[ht] = d;
    }
    #pragma unroll
    for (int ht = 0; ht < 16; ++ht) {
        const f32x4 bv = *(const f32x4*)(b1 + ht * 16 + q * 4);
        u32x2 pk;
        pk[0] = pack2bf(gelu_exact(Ht[ht][0] + bv[0]), gelu_exact(Ht[ht][1] + bv[1]));
        pk[1] = pack2bf(gelu_exact(Ht[ht][2] + bv[2]), gelu_exact(Ht[ht][3] + bv[3]));
        *(u32x2*)(hp + m * 264 + ht * 16 + q * 4) = pk;
    }
    f32x4 F[4];
    #pragma unroll
    for (int nt = 0; nt < 4; ++nt) F[nt] = (f32x4){0.0f, 0.0f, 0.0f, 0.0f};
    #pragma unroll
    for (int kt = 0; kt < 8; ++kt) {
        V4S8 af;
        af.u = *(const u32x4*)(hp + m * 264 + kt * 32 + q * 8);
        #pragma unroll
        for (int nt = 0; nt < 4; ++nt) {
            V4S8 bf_;
            bf_.u = *(const u32x4*)(w2tb + (nt * 16 + m) * 256 + kt * 32 + q * 8);
            F[nt] = __builtin_amdgcn_mfma_f32_16x16x32_bf16(af.s, bf_.s, F[nt], 0, 0, 0);
        }
    }
    float* ob = out + (size_t)b * (64 * HW);
    #pragma unroll
    for (int nt = 0; nt < 4; ++nt) {
        int co = nt * 16 + m;
        float bias = b2[co];
        f32x4 r;
        #pragma unroll
        for (int k = 0; k < 4; ++k) r[k] = acc[nt][k] + F[nt][k] + bias;
        *(f32x4*)(ob + (size_t)co * HW + pp0 + (w * 16 + q * 4)) = r;
    }
}

extern "C" void kernel_launch(void* const* d_in, const int* in_sizes, int n_in,
                              void* d_out, int out_size, void* d_ws, size_t ws_size,
                              hipStream_t stream) {
    const float* R      = (const float*)d_in[0];
    const float* off_w1 = (const float*)d_in[1];
    const float* off_b1 = (const float*)d_in[2];
    const float* off_w2 = (const float*)d_in[3];
    const float* off_b2 = (const float*)d_in[4];
    const float* w_sub[4] = {(const float*)d_in[5], (const float*)d_in[7],
                             (const float*)d_in[9], (const float*)d_in[11]};
    const float* b_sub[4] = {(const float*)d_in[6], (const float*)d_in[8],
                             (const float*)d_in[10], (const float*)d_in[12]};
    const float* ln_w   = (const float*)d_in[13];
    const float* ln_b   = (const float*)d_in[14];
    const float* ffn_w1 = (const float*)d_in[15];
    const float* ffn_b1 = (const float*)d_in[16];
    const float* ffn_w2 = (const float*)d_in[17];
    const float* ffn_b2 = (const float*)d_in[18];
    const float* fus_w  = (const float*)d_in[19];
    const float* fus_b  = (const float*)d_in[20];

    // ws layout (floats), total 25,678,848 f = 102.7 MB (within round-5 footprint):
    float* ws = (float*)d_ws;
    unsigned short* fbuf = (unsigned short*)ws;          // [4][4][64][HW] bf16 = 8,388,608 f
    float* ll_p = ws + 8388608;                          // 4,194,304 f
    float* o1   = ws + 8388608;                          // 8,388,608 f (dead before ll_p/hb written)
    float* hb   = ws + 12582912;                         // 12,582,912 f (ends 25,165,824)
    float* disp = ws + 25165824;                         // 393,216 f
    float* w4_off2 = ws + 25559040;                      // 3,072 f
    unsigned short* w1b        = (unsigned short*)(ws + 25562112);  // 16,384 s
    unsigned short* w2tb       = (unsigned short*)(ws + 25570304);  // 16,384 s
    unsigned short* fus_wb     = (unsigned short*)(ws + 25578496);  // 16,384 s
    unsigned short* wb_sub     = (unsigned short*)(ws + 25586688);  // 147,456 s
    unsigned short* wb_off1    = (unsigned short*)(ws + 25660416);  // 18,432 s
    unsigned short* wb_off1_lo = (unsigned short*)(ws + 25669632);  // 18,432 s

    prep_weights<<<852, 256, 0, stream>>>(ffn_w1, w1b, ffn_w2, w2tb, fus_w, fus_wb,
                                          w_sub[0], w_sub[1], w_sub[2], w_sub[3], wb_sub,
                                          off_w1, wb_off1, wb_off1_lo, off_w2, w4_off2);
    conv_off_split<<<1024, 256, 0, stream>>>(R, wb_off1, wb_off1_lo, off_b1, o1);
    conv2_pool_tiled<<<256, 256, 0, stream>>>(o1, w4_off2, off_b2, disp);
    dwt_kernel<<<16384, 256, 0, stream>>>(R, ll_p, hb);
    subband_fused<<<1024, 256, 0, stream>>>(ll_p, hb, disp, wb_sub,
                                            b_sub[0], b_sub[1], b_sub[2], b_sub[3], fbuf,
                                            ln_w, ln_b, w1b, ffn_b1, w2tb, ffn_b2);
    fus_ln_ffn<<<1024, 256, 0, stream>>>(fbuf, fus_wb, fus_b, (float*)d_out,
                                         ln_w, ln_b, w1b, ffn_b1, w2tb, ffn_b2);
}